// Round 2
// baseline (1212.837 us; speedup 1.0000x reference)
//
#include <hip/hip_runtime.h>
#include <math.h>

#define SB 4
#define CC 48
#define NH 8
#define HDIM 6
#define NPIX 4096
#define NE 16
#define TD 512

__device__ __forceinline__ float wave_sum(float t){
#pragma unroll
  for (int o = 32; o >= 1; o >>= 1) t += __shfl_xor(t, o, 64);
  return t;
}

// ---------------- K1: LN1 + qkv 1x1 + router 1x1 (fused, per-pixel) -------------
__global__ __launch_bounds__(256) void k_ln_qkv_router(
    const float* __restrict__ x, const float* __restrict__ ln1w, const float* __restrict__ ln1b,
    const float* __restrict__ qkvw, const float* __restrict__ routw,
    float* __restrict__ qkv_raw, float* __restrict__ rl)
{
  __shared__ __align__(16) float wq[144*CC];
  __shared__ __align__(16) float wr[NH*CC];
  int tid = threadIdx.x;
  for (int i = tid; i < 144*CC; i += 256) wq[i] = qkvw[i];
  for (int i = tid; i < NH*CC; i += 256) wr[i] = routw[i];
  __syncthreads();
  int b = blockIdx.y;
  int p = blockIdx.x*256 + tid;
  const float* xb = x + (size_t)b*CC*NPIX + p;
  float v[CC];
  float mu = 0.f;
#pragma unroll
  for (int c = 0; c < CC; c++){ v[c] = xb[(size_t)c*NPIX]; mu += v[c]; }
  mu *= (1.f/CC);
  float var = 0.f;
#pragma unroll
  for (int c = 0; c < CC; c++){ float d = v[c]-mu; var += d*d; }
  var *= (1.f/CC);
  float rs = rsqrtf(var + 1e-5f);
#pragma unroll
  for (int c = 0; c < CC; c++) v[c] = (v[c]-mu)*rs*ln1w[c] + ln1b[c];

  float* qo = qkv_raw + (size_t)b*144*NPIX + p;
  for (int oc = 0; oc < 144; oc++){
    const float* w = &wq[oc*CC];
    float acc = 0.f;
#pragma unroll
    for (int c = 0; c < CC; c++) acc += w[c]*v[c];
    qo[(size_t)oc*NPIX] = acc;
  }
  float* ro = rl + (size_t)b*NH*NPIX + p;
  for (int h = 0; h < NH; h++){
    const float* w = &wr[h*CC];
    float acc = 0.f;
#pragma unroll
    for (int c = 0; c < CC; c++) acc += w[c]*v[c];
    ro[(size_t)h*NPIX] = acc;
  }
}

// ---------------- K2: depthwise 3x3, pad 1 --------------------------------------
__global__ __launch_bounds__(256) void k_dwconv(
    const float* __restrict__ in, const float* __restrict__ w, float* __restrict__ out)
{
  int ch = blockIdx.y, b = blockIdx.z;
  int p = blockIdx.x*256 + threadIdx.x;
  int y = p >> 6, xx = p & 63;
  const float* wc = w + ch*9;
  const float* ib = in + ((size_t)b*144 + ch)*NPIX;
  float acc = 0.f;
#pragma unroll
  for (int ky = 0; ky < 3; ky++){
    int yy = y + ky - 1;
    if ((unsigned)yy < 64u){
#pragma unroll
      for (int kx = 0; kx < 3; kx++){
        int xc = xx + kx - 1;
        if ((unsigned)xc < 64u) acc += wc[ky*3+kx]*ib[yy*64+xc];
      }
    }
  }
  out[((size_t)b*144 + ch)*NPIX + p] = acc;
}

// ---------------- K3: per-pixel head routing: softmax(8) + top2 renorm ----------
__global__ __launch_bounds__(256) void k_router_gates(
    const float* __restrict__ rl, float* __restrict__ g)
{
  int idx = blockIdx.x*256 + threadIdx.x;   // over SB*NPIX
  int b = idx >> 12, p = idx & (NPIX-1);
  const float* r = rl + (size_t)b*NH*NPIX + p;
  float l[NH];
  float mx = -1e30f;
#pragma unroll
  for (int h = 0; h < NH; h++){ l[h] = r[(size_t)h*NPIX]; mx = fmaxf(mx, l[h]); }
  float s = 0.f;
#pragma unroll
  for (int h = 0; h < NH; h++){ l[h] = __expf(l[h]-mx); s += l[h]; }
  int i1 = 0; float p1 = -1.f;
#pragma unroll
  for (int h = 0; h < NH; h++) if (l[h] > p1){ p1 = l[h]; i1 = h; }
  int i2 = -1; float p2 = -1.f;
#pragma unroll
  for (int h = 0; h < NH; h++) if (h != i1 && l[h] > p2){ p2 = l[h]; i2 = h; }
  float denom = p1 + p2;
  float* go = g + (size_t)b*NH*NPIX + p;
#pragma unroll
  for (int h = 0; h < NH; h++)
    go[(size_t)h*NPIX] = (h == i1 || h == i2) ? l[h]/denom : 0.f;
}

// ---------------- K4: per-(b,h) attention: norms + gram + softmax + PV + gate ---
__global__ __launch_bounds__(256) void k_attn(
    const float* __restrict__ qkv, const float* __restrict__ g, float* __restrict__ out)
{
  int h = blockIdx.x, b = blockIdx.y;
  const float* q = qkv + ((size_t)b*144 + h*HDIM)*NPIX;
  const float* k = qkv + ((size_t)b*144 + 48 + h*HDIM)*NPIX;
  const float* v = qkv + ((size_t)b*144 + 96 + h*HDIM)*NPIX;
  int tid = threadIdx.x;
  float qq[HDIM] = {0}, kk[HDIM] = {0}, qk[HDIM*HDIM] = {0};
  for (int n = tid; n < NPIX; n += 256){
    float qv[HDIM], kv[HDIM];
#pragma unroll
    for (int c = 0; c < HDIM; c++){ qv[c] = q[(size_t)c*NPIX + n]; kv[c] = k[(size_t)c*NPIX + n]; }
#pragma unroll
    for (int c = 0; c < HDIM; c++){
      qq[c] += qv[c]*qv[c]; kk[c] += kv[c]*kv[c];
#pragma unroll
      for (int d = 0; d < HDIM; d++) qk[c*HDIM+d] += qv[c]*kv[d];
    }
  }
#pragma unroll
  for (int c = 0; c < HDIM; c++){ qq[c] = wave_sum(qq[c]); kk[c] = wave_sum(kk[c]); }
#pragma unroll
  for (int i = 0; i < HDIM*HDIM; i++) qk[i] = wave_sum(qk[i]);

  __shared__ float red[4][48];
  __shared__ float tot[48];
  __shared__ float sm[HDIM][HDIM];
  int lane = tid & 63, wv = tid >> 6;
  if (lane == 0){
#pragma unroll
    for (int c = 0; c < HDIM; c++){ red[wv][c] = qq[c]; red[wv][6+c] = kk[c]; }
#pragma unroll
    for (int i = 0; i < HDIM*HDIM; i++) red[wv][12+i] = qk[i];
  }
  __syncthreads();
  if (tid < 48) tot[tid] = red[0][tid]+red[1][tid]+red[2][tid]+red[3][tid];
  __syncthreads();
  if (tid < HDIM){
    int c = tid;
    float qn = fmaxf(sqrtf(tot[c]), 1e-12f);
    float row[HDIM];
    float mx = -1e30f;
#pragma unroll
    for (int d = 0; d < HDIM; d++){
      float kn = fmaxf(sqrtf(tot[6+d]), 1e-12f);
      float a = tot[12 + c*HDIM + d] / (qn*kn) * 0.40824829046386307f; // 6^-0.5
      row[d] = a; mx = fmaxf(mx, a);
    }
    float s = 0.f;
#pragma unroll
    for (int d = 0; d < HDIM; d++){ row[d] = __expf(row[d]-mx); s += row[d]; }
#pragma unroll
    for (int d = 0; d < HDIM; d++) sm[c][d] = row[d]/s;
  }
  __syncthreads();
  const float* gb = g + ((size_t)b*NH + h)*NPIX;
  float* ob = out + ((size_t)b*CC + h*HDIM)*NPIX;
  for (int n = tid; n < NPIX; n += 256){
    float vv[HDIM];
#pragma unroll
    for (int d = 0; d < HDIM; d++) vv[d] = v[(size_t)d*NPIX + n];
    float gg = gb[n];
#pragma unroll
    for (int c = 0; c < HDIM; c++){
      float o = 0.f;
#pragma unroll
      for (int d = 0; d < HDIM; d++) o += sm[c][d]*vv[d];
      ob[(size_t)c*NPIX + n] = o*gg;
    }
  }
}

// ---------------- K5: proj 1x1 + residual + LN2 (fused, per-pixel) --------------
__global__ __launch_bounds__(256) void k_proj_ln2(
    const float* __restrict__ attn_out, const float* __restrict__ x,
    const float* __restrict__ projw, const float* __restrict__ ln2w, const float* __restrict__ ln2b,
    float* __restrict__ xout, float* __restrict__ y2)
{
  __shared__ __align__(16) float w[CC*CC];
  int tid = threadIdx.x;
  for (int i = tid; i < CC*CC; i += 256) w[i] = projw[i];
  __syncthreads();
  int b = blockIdx.y;
  int p = blockIdx.x*256 + tid;
  const float* ain = attn_out + (size_t)b*CC*NPIX + p;
  float a[CC];
#pragma unroll
  for (int c = 0; c < CC; c++) a[c] = ain[(size_t)c*NPIX];
  const float* xb = x + (size_t)b*CC*NPIX + p;
  float xv[CC];
  float mu = 0.f;
#pragma unroll
  for (int oc = 0; oc < CC; oc++){
    const float* wr = &w[oc*CC];
    float acc = 0.f;
#pragma unroll
    for (int c = 0; c < CC; c++) acc += wr[c]*a[c];
    float t = xb[(size_t)oc*NPIX] + acc;
    xv[oc] = t; mu += t;
  }
  mu *= (1.f/CC);
  float var = 0.f;
#pragma unroll
  for (int c = 0; c < CC; c++){ float d = xv[c]-mu; var += d*d; }
  var *= (1.f/CC);
  float rs = rsqrtf(var + 1e-5f);
  float* xo = xout + (size_t)b*CC*NPIX + p;
  float* yo = y2 + (size_t)b*CC*NPIX + p;
#pragma unroll
  for (int c = 0; c < CC; c++){
    xo[(size_t)c*NPIX] = xv[c];
    yo[(size_t)c*NPIX] = (xv[c]-mu)*rs*ln2w[c] + ln2b[c];
  }
}

// ---------------- K_pool: pooled[b][c] = mean over pixels of y2 -----------------
__global__ __launch_bounds__(256) void k_pool(const float* __restrict__ y2, float* __restrict__ pooled)
{
  int bc = blockIdx.x;
  const float* r = y2 + (size_t)bc*NPIX;
  float s = 0.f;
  for (int n = threadIdx.x; n < NPIX; n += 256) s += r[n];
  s = wave_sum(s);
  __shared__ float red[4];
  int lane = threadIdx.x & 63, wv = threadIdx.x >> 6;
  if (lane == 0) red[wv] = s;
  __syncthreads();
  if (threadIdx.x == 0) pooled[bc] = (red[0]+red[1]+red[2]+red[3]) * (1.f/NPIX);
}

// ---------------- K6: MoE gate: logits + softmax(16) + top2 renorm --------------
__global__ __launch_bounds__(64) void k_moe_gate(
    const float* __restrict__ pooled, const float* __restrict__ text,
    const float* __restrict__ gwx, const float* __restrict__ gwt, float* __restrict__ gates)
{
  int tid = threadIdx.x;
  int b = tid >> 4, e = tid & 15;
  float acc = 0.f;
  for (int c = 0; c < CC; c++) acc += pooled[b*CC + c]*gwx[c*NE + e];
  for (int d = 0; d < TD; d++) acc += text[b*TD + d]*gwt[d*NE + e];
  __shared__ float lg[SB][NE];
  lg[b][e] = acc;
  __syncthreads();
  if (tid < SB){
    int bb = tid;
    float mx = -1e30f;
    for (int i = 0; i < NE; i++) mx = fmaxf(mx, lg[bb][i]);
    float ex[NE]; float s = 0.f;
    for (int i = 0; i < NE; i++){ ex[i] = __expf(lg[bb][i]-mx); s += ex[i]; }
    int i1 = 0; float p1 = -1.f;
    for (int i = 0; i < NE; i++) if (ex[i] > p1){ p1 = ex[i]; i1 = i; }
    int i2 = -1; float p2 = -1.f;
    for (int i = 0; i < NE; i++) if (i != i1 && ex[i] > p2){ p2 = ex[i]; i2 = i; }
    float denom = p1 + p2;
    for (int i = 0; i < NE; i++)
      gates[bb*NE + i] = (i == i1 || i == i2) ? ex[i]/denom : 0.f;
  }
}

// ---------------- Expert conv kernels -------------------------------------------
// TYPE 0: input = y2 at 64x64. TYPE 1: nearest-up x2 -> 128x128. TYPE 2: maxpool -> 32x32.
template<int TYPE>
__global__ __launch_bounds__(256) void k_expert_conv1(
    const float* __restrict__ y2, const float* __restrict__ w1, const float* __restrict__ b1,
    const float* __restrict__ gates, int e, float* __restrict__ h_buf)
{
  int b = blockIdx.y;
  if (gates[b*NE + e] == 0.f) return;
  constexpr int S = (TYPE==1) ? 128 : ((TYPE==2) ? 32 : 64);
  __shared__ __align__(16) float wl[CC*9*CC];   // [ic*9+k][oc]
  const float* wg = w1 + (size_t)e*CC*CC*9;
  for (int i = threadIdx.x; i < CC*CC*9; i += 256){
    int oc = i / (CC*9); int r = i % (CC*9);
    wl[r*CC + oc] = wg[i];
  }
  __syncthreads();
  int p = blockIdx.x*256 + threadIdx.x;
  int oy = p / S, ox = p % S;
  float acc[CC];
#pragma unroll
  for (int oc = 0; oc < CC; oc++) acc[oc] = b1[e*CC + oc];
  const float* yb = y2 + (size_t)b*CC*NPIX;
  for (int ic = 0; ic < CC; ic++){
    const float* yc = yb + (size_t)ic*NPIX;
    float z[9];
#pragma unroll
    for (int ky = 0; ky < 3; ky++){
#pragma unroll
      for (int kx = 0; kx < 3; kx++){
        int yy = oy + ky - 1, xx = ox + kx - 1;
        float zz = 0.f;
        if ((unsigned)yy < (unsigned)S && (unsigned)xx < (unsigned)S){
          if (TYPE == 0) zz = yc[yy*64 + xx];
          else if (TYPE == 1) zz = yc[(yy>>1)*64 + (xx>>1)];
          else {
            int y0 = yy*2, x0 = xx*2;
            zz = fmaxf(fmaxf(yc[y0*64+x0], yc[y0*64+x0+1]),
                       fmaxf(yc[(y0+1)*64+x0], yc[(y0+1)*64+x0+1]));
          }
        }
        z[ky*3+kx] = zz;
      }
    }
#pragma unroll
    for (int k = 0; k < 9; k++){
      const float* wrow = &wl[(ic*9 + k)*CC];
      float zz = z[k];
#pragma unroll
      for (int oc = 0; oc < CC; oc++) acc[oc] += zz*wrow[oc];
    }
  }
  float* hb = h_buf + (size_t)b*CC*S*S + p;
#pragma unroll
  for (int oc = 0; oc < CC; oc++){
    float t = acc[oc];
    hb[(size_t)oc*S*S] = 0.5f*t*(1.f + erff(t*0.70710678118654752f));  // exact gelu
  }
}

template<int S>
__global__ __launch_bounds__(256) void k_expert_conv2(
    const float* __restrict__ h_buf, const float* __restrict__ w2, const float* __restrict__ b2,
    const float* __restrict__ gates, int e, float* __restrict__ he_buf)
{
  int b = blockIdx.y;
  if (gates[b*NE + e] == 0.f) return;
  __shared__ __align__(16) float wl[CC*9*CC];
  const float* wg = w2 + (size_t)e*CC*CC*9;
  for (int i = threadIdx.x; i < CC*CC*9; i += 256){
    int oc = i / (CC*9); int r = i % (CC*9);
    wl[r*CC + oc] = wg[i];
  }
  __syncthreads();
  int p = blockIdx.x*256 + threadIdx.x;
  int oy = p / S, ox = p % S;
  float acc[CC];
#pragma unroll
  for (int oc = 0; oc < CC; oc++) acc[oc] = b2[e*CC + oc];
  const float* hb = h_buf + (size_t)b*CC*S*S;
  for (int ic = 0; ic < CC; ic++){
    const float* hc = hb + (size_t)ic*S*S;
    float z[9];
#pragma unroll
    for (int ky = 0; ky < 3; ky++){
#pragma unroll
      for (int kx = 0; kx < 3; kx++){
        int yy = oy + ky - 1, xx = ox + kx - 1;
        z[ky*3+kx] = ((unsigned)yy < (unsigned)S && (unsigned)xx < (unsigned)S) ? hc[yy*S + xx] : 0.f;
      }
    }
#pragma unroll
    for (int k = 0; k < 9; k++){
      const float* wrow = &wl[(ic*9 + k)*CC];
      float zz = z[k];
#pragma unroll
      for (int oc = 0; oc < CC; oc++) acc[oc] += zz*wrow[oc];
    }
  }
  float* ho = he_buf + (size_t)b*CC*S*S + p;
#pragma unroll
  for (int oc = 0; oc < CC; oc++) ho[(size_t)oc*S*S] = acc[oc];
}

// ---------------- Combine kernels (gate * post-transform, accumulate) -----------
__global__ __launch_bounds__(256) void k_comb0(
    const float* __restrict__ he, const float* __restrict__ gates, int e, float* __restrict__ out)
{
  int b = blockIdx.z, c = blockIdx.y;
  float gt = gates[b*NE + e];
  if (gt == 0.f) return;
  int p = blockIdx.x*256 + threadIdx.x;
  size_t i = ((size_t)b*CC + c)*NPIX + p;
  out[i] += gt*he[i];
}

__global__ __launch_bounds__(256) void k_comb1(
    const float* __restrict__ he, const float* __restrict__ gates, int e, float* __restrict__ out)
{
  int b = blockIdx.z, c = blockIdx.y;
  float gt = gates[b*NE + e];
  if (gt == 0.f) return;
  int p = blockIdx.x*256 + threadIdx.x;
  int y = p >> 6, x = p & 63;
  const float* h = he + ((size_t)b*CC + c)*16384;
  int y0 = 2*y, x0 = 2*x;
  float m = fmaxf(fmaxf(h[y0*128+x0], h[y0*128+x0+1]),
                  fmaxf(h[(y0+1)*128+x0], h[(y0+1)*128+x0+1]));
  out[((size_t)b*CC + c)*NPIX + p] += gt*m;
}

__device__ __forceinline__ void bl_coord(int o, int& i0, int& i1, float& w0, float& w1){
  float f = 0.5f*o - 0.25f;
  float fl = floorf(f);
  int i = (int)fl;
  float fr = f - fl;
  i0 = i < 0 ? 0 : i;
  int j = i + 1;
  i1 = j > 31 ? 31 : j;
  w0 = 1.f - fr; w1 = fr;
}

__global__ __launch_bounds__(256) void k_comb2(
    const float* __restrict__ he, const float* __restrict__ gates, int e, float* __restrict__ out)
{
  int b = blockIdx.z, c = blockIdx.y;
  float gt = gates[b*NE + e];
  if (gt == 0.f) return;
  int p = blockIdx.x*256 + threadIdx.x;
  int y = p >> 6, x = p & 63;
  int y0,y1,x0,x1; float wy0,wy1,wx0,wx1;
  bl_coord(y, y0, y1, wy0, wy1);
  bl_coord(x, x0, x1, wx0, wx1);
  const float* h = he + ((size_t)b*CC + c)*1024;
  float v = wy0*(wx0*h[y0*32+x0] + wx1*h[y0*32+x1])
          + wy1*(wx0*h[y1*32+x0] + wx1*h[y1*32+x1]);
  out[((size_t)b*CC + c)*NPIX + p] += gt*v;
}

// ---------------- launch ---------------------------------------------------------
extern "C" void kernel_launch(void* const* d_in, const int* in_sizes, int n_in,
                              void* d_out, int out_size, void* d_ws, size_t ws_size,
                              hipStream_t stream) {
  const float* x      = (const float*)d_in[0];
  const float* text   = (const float*)d_in[1];
  // d_in[2] = task_id (unused; task-0 router weights are what's passed)
  const float* ln1w   = (const float*)d_in[3];
  const float* ln1b   = (const float*)d_in[4];
  const float* ln2w   = (const float*)d_in[5];
  const float* ln2b   = (const float*)d_in[6];
  const float* qkvw   = (const float*)d_in[7];
  const float* qkvdw  = (const float*)d_in[8];
  const float* projw  = (const float*)d_in[9];
  const float* routw  = (const float*)d_in[10];
  const float* gwx    = (const float*)d_in[11];
  const float* gwt    = (const float*)d_in[12];
  const float* ew1    = (const float*)d_in[13];
  const float* eb1    = (const float*)d_in[14];
  const float* ew2    = (const float*)d_in[15];
  const float* eb2    = (const float*)d_in[16];
  float* out = (float*)d_out;

  float* wsf = (float*)d_ws;
  float* y2      = wsf;                    // 786432
  float* pooled  = y2 + 786432;            // 192
  float* gates   = pooled + 192;           // 64
  float* R       = gates + 64;             // overlapped region
  float* qkv_raw = R;                      // 2359296
  float* qkv_dw  = R + 2359296;            // 2359296
  float* rl      = qkv_dw + 2359296;       // 131072
  float* gmask   = rl + 131072;            // 131072
  float* attnout = gmask + 131072;         // 786432
  float* h_buf   = R;                      // 3145728 (aliases dead qkv_raw/...)
  float* he_buf  = R + 3145728;            // 3145728 (aliases dead qkv_dw/rl/g/attnout)

  k_ln_qkv_router<<<dim3(16, SB), 256, 0, stream>>>(x, ln1w, ln1b, qkvw, routw, qkv_raw, rl);
  k_dwconv<<<dim3(16, 144, SB), 256, 0, stream>>>(qkv_raw, qkvdw, qkv_dw);
  k_router_gates<<<dim3(64), 256, 0, stream>>>(rl, gmask);
  k_attn<<<dim3(NH, SB), 256, 0, stream>>>(qkv_dw, gmask, attnout);
  k_proj_ln2<<<dim3(16, SB), 256, 0, stream>>>(attnout, x, projw, ln2w, ln2b, out, y2);
  k_pool<<<dim3(SB*CC), 256, 0, stream>>>(y2, pooled);
  k_moe_gate<<<dim3(1), 64, 0, stream>>>(pooled, text, gwx, gwt, gates);

  for (int e = 0; e < NE; e++){
    int t = e % 3;
    if (t == 0){
      k_expert_conv1<0><<<dim3(16, SB), 256, 0, stream>>>(y2, ew1, eb1, gates, e, h_buf);
      k_expert_conv2<64><<<dim3(16, SB), 256, 0, stream>>>(h_buf, ew2, eb2, gates, e, he_buf);
      k_comb0<<<dim3(16, CC, SB), 256, 0, stream>>>(he_buf, gates, e, out);
    } else if (t == 1){
      k_expert_conv1<1><<<dim3(64, SB), 256, 0, stream>>>(y2, ew1, eb1, gates, e, h_buf);
      k_expert_conv2<128><<<dim3(64, SB), 256, 0, stream>>>(h_buf, ew2, eb2, gates, e, he_buf);
      k_comb1<<<dim3(16, CC, SB), 256, 0, stream>>>(he_buf, gates, e, out);
    } else {
      k_expert_conv1<2><<<dim3(4, SB), 256, 0, stream>>>(y2, ew1, eb1, gates, e, h_buf);
      k_expert_conv2<32><<<dim3(4, SB), 256, 0, stream>>>(h_buf, ew2, eb2, gates, e, he_buf);
      k_comb2<<<dim3(16, CC, SB), 256, 0, stream>>>(he_buf, gates, e, out);
    }
  }
  (void)in_sizes; (void)n_in; (void)out_size; (void)ws_size;
}

// Round 4
// 629.464 us; speedup vs baseline: 1.9268x; 1.9268x over previous
//
#include <hip/hip_runtime.h>
#include <math.h>

#define SB 4
#define CC 48
#define NH 8
#define HDIM 6
#define NPIX 4096
#define NE 16
#define TD 512

__device__ __forceinline__ float wave_sum(float t){
#pragma unroll
  for (int o = 32; o >= 1; o >>= 1) t += __shfl_xor(t, o, 64);
  return t;
}

// ---------------- K1: LN1 + qkv 1x1 + router 1x1 (fused, per-pixel) -------------
__global__ __launch_bounds__(256) void k_ln_qkv_router(
    const float* __restrict__ x, const float* __restrict__ ln1w, const float* __restrict__ ln1b,
    const float* __restrict__ qkvw, const float* __restrict__ routw,
    float* __restrict__ qkv_raw, float* __restrict__ rl)
{
  __shared__ __align__(16) float wq[144*CC];
  __shared__ __align__(16) float wr[NH*CC];
  int tid = threadIdx.x;
  for (int i = tid; i < 144*CC; i += 256) wq[i] = qkvw[i];
  for (int i = tid; i < NH*CC; i += 256) wr[i] = routw[i];
  __syncthreads();
  int b = blockIdx.y;
  int p = blockIdx.x*256 + tid;
  const float* xb = x + (size_t)b*CC*NPIX + p;
  float v[CC];
  float mu = 0.f;
#pragma unroll
  for (int c = 0; c < CC; c++){ v[c] = xb[(size_t)c*NPIX]; mu += v[c]; }
  mu *= (1.f/CC);
  float var = 0.f;
#pragma unroll
  for (int c = 0; c < CC; c++){ float d = v[c]-mu; var += d*d; }
  var *= (1.f/CC);
  float rs = rsqrtf(var + 1e-5f);
#pragma unroll
  for (int c = 0; c < CC; c++) v[c] = (v[c]-mu)*rs*ln1w[c] + ln1b[c];

  float* qo = qkv_raw + (size_t)b*144*NPIX + p;
  for (int oc = 0; oc < 144; oc++){
    const float* w = &wq[oc*CC];
    float acc = 0.f;
#pragma unroll
    for (int c = 0; c < CC; c++) acc += w[c]*v[c];
    qo[(size_t)oc*NPIX] = acc;
  }
  float* ro = rl + (size_t)b*NH*NPIX + p;
  for (int h = 0; h < NH; h++){
    const float* w = &wr[h*CC];
    float acc = 0.f;
#pragma unroll
    for (int c = 0; c < CC; c++) acc += w[c]*v[c];
    ro[(size_t)h*NPIX] = acc;
  }
}

// ---------------- K2: depthwise 3x3, pad 1 --------------------------------------
__global__ __launch_bounds__(256) void k_dwconv(
    const float* __restrict__ in, const float* __restrict__ w, float* __restrict__ out)
{
  int ch = blockIdx.y, b = blockIdx.z;
  int p = blockIdx.x*256 + threadIdx.x;
  int y = p >> 6, xx = p & 63;
  const float* wc = w + ch*9;
  const float* ib = in + ((size_t)b*144 + ch)*NPIX;
  float acc = 0.f;
#pragma unroll
  for (int ky = 0; ky < 3; ky++){
    int yy = y + ky - 1;
    if ((unsigned)yy < 64u){
#pragma unroll
      for (int kx = 0; kx < 3; kx++){
        int xc = xx + kx - 1;
        if ((unsigned)xc < 64u) acc += wc[ky*3+kx]*ib[yy*64+xc];
      }
    }
  }
  out[((size_t)b*144 + ch)*NPIX + p] = acc;
}

// ---------------- K3: per-pixel head routing: softmax(8) + top2 renorm ----------
__global__ __launch_bounds__(256) void k_router_gates(
    const float* __restrict__ rl, float* __restrict__ g)
{
  int idx = blockIdx.x*256 + threadIdx.x;   // over SB*NPIX
  int b = idx >> 12, p = idx & (NPIX-1);
  const float* r = rl + (size_t)b*NH*NPIX + p;
  float l[NH];
  float mx = -1e30f;
#pragma unroll
  for (int h = 0; h < NH; h++){ l[h] = r[(size_t)h*NPIX]; mx = fmaxf(mx, l[h]); }
  float s = 0.f;
#pragma unroll
  for (int h = 0; h < NH; h++){ l[h] = __expf(l[h]-mx); s += l[h]; }
  int i1 = 0; float p1 = -1.f;
#pragma unroll
  for (int h = 0; h < NH; h++) if (l[h] > p1){ p1 = l[h]; i1 = h; }
  int i2 = -1; float p2 = -1.f;
#pragma unroll
  for (int h = 0; h < NH; h++) if (h != i1 && l[h] > p2){ p2 = l[h]; i2 = h; }
  float denom = p1 + p2;
  float* go = g + (size_t)b*NH*NPIX + p;
#pragma unroll
  for (int h = 0; h < NH; h++)
    go[(size_t)h*NPIX] = (h == i1 || h == i2) ? l[h]/denom : 0.f;
}

// ---------------- K4: per-(b,h) attention -----------------------------------------
__global__ __launch_bounds__(256) void k_attn(
    const float* __restrict__ qkv, const float* __restrict__ g, float* __restrict__ out)
{
  int h = blockIdx.x, b = blockIdx.y;
  const float* q = qkv + ((size_t)b*144 + h*HDIM)*NPIX;
  const float* k = qkv + ((size_t)b*144 + 48 + h*HDIM)*NPIX;
  const float* v = qkv + ((size_t)b*144 + 96 + h*HDIM)*NPIX;
  int tid = threadIdx.x;
  float qq[HDIM] = {0}, kk[HDIM] = {0}, qk[HDIM*HDIM] = {0};
  for (int n = tid; n < NPIX; n += 256){
    float qv[HDIM], kv[HDIM];
#pragma unroll
    for (int c = 0; c < HDIM; c++){ qv[c] = q[(size_t)c*NPIX + n]; kv[c] = k[(size_t)c*NPIX + n]; }
#pragma unroll
    for (int c = 0; c < HDIM; c++){
      qq[c] += qv[c]*qv[c]; kk[c] += kv[c]*kv[c];
#pragma unroll
      for (int d = 0; d < HDIM; d++) qk[c*HDIM+d] += qv[c]*kv[d];
    }
  }
#pragma unroll
  for (int c = 0; c < HDIM; c++){ qq[c] = wave_sum(qq[c]); kk[c] = wave_sum(kk[c]); }
#pragma unroll
  for (int i = 0; i < HDIM*HDIM; i++) qk[i] = wave_sum(qk[i]);

  __shared__ float red[4][48];
  __shared__ float tot[48];
  __shared__ float sm[HDIM][HDIM];
  int lane = tid & 63, wv = tid >> 6;
  if (lane == 0){
#pragma unroll
    for (int c = 0; c < HDIM; c++){ red[wv][c] = qq[c]; red[wv][6+c] = kk[c]; }
#pragma unroll
    for (int i = 0; i < HDIM*HDIM; i++) red[wv][12+i] = qk[i];
  }
  __syncthreads();
  if (tid < 48) tot[tid] = red[0][tid]+red[1][tid]+red[2][tid]+red[3][tid];
  __syncthreads();
  if (tid < HDIM){
    int c = tid;
    float qn = fmaxf(sqrtf(tot[c]), 1e-12f);
    float row[HDIM];
    float mx = -1e30f;
#pragma unroll
    for (int d = 0; d < HDIM; d++){
      float kn = fmaxf(sqrtf(tot[6+d]), 1e-12f);
      float a = tot[12 + c*HDIM + d] / (qn*kn) * 0.40824829046386307f; // 6^-0.5
      row[d] = a; mx = fmaxf(mx, a);
    }
    float s = 0.f;
#pragma unroll
    for (int d = 0; d < HDIM; d++){ row[d] = __expf(row[d]-mx); s += row[d]; }
#pragma unroll
    for (int d = 0; d < HDIM; d++) sm[c][d] = row[d]/s;
  }
  __syncthreads();
  const float* gb = g + ((size_t)b*NH + h)*NPIX;
  float* ob = out + ((size_t)b*CC + h*HDIM)*NPIX;
  for (int n = tid; n < NPIX; n += 256){
    float vv[HDIM];
#pragma unroll
    for (int d = 0; d < HDIM; d++) vv[d] = v[(size_t)d*NPIX + n];
    float gg = gb[n];
#pragma unroll
    for (int c = 0; c < HDIM; c++){
      float o = 0.f;
#pragma unroll
      for (int d = 0; d < HDIM; d++) o += sm[c][d]*vv[d];
      ob[(size_t)c*NPIX + n] = o*gg;
    }
  }
}

// ---------------- K5: proj 1x1 + residual + LN2 ----------------------------------
__global__ __launch_bounds__(256) void k_proj_ln2(
    const float* __restrict__ attn_out, const float* __restrict__ x,
    const float* __restrict__ projw, const float* __restrict__ ln2w, const float* __restrict__ ln2b,
    float* __restrict__ xout, float* __restrict__ y2)
{
  __shared__ __align__(16) float w[CC*CC];
  int tid = threadIdx.x;
  for (int i = tid; i < CC*CC; i += 256) w[i] = projw[i];
  __syncthreads();
  int b = blockIdx.y;
  int p = blockIdx.x*256 + tid;
  const float* ain = attn_out + (size_t)b*CC*NPIX + p;
  float a[CC];
#pragma unroll
  for (int c = 0; c < CC; c++) a[c] = ain[(size_t)c*NPIX];
  const float* xb = x + (size_t)b*CC*NPIX + p;
  float xv[CC];
  float mu = 0.f;
#pragma unroll
  for (int oc = 0; oc < CC; oc++){
    const float* wr = &w[oc*CC];
    float acc = 0.f;
#pragma unroll
    for (int c = 0; c < CC; c++) acc += wr[c]*a[c];
    float t = xb[(size_t)oc*NPIX] + acc;
    xv[oc] = t; mu += t;
  }
  mu *= (1.f/CC);
  float var = 0.f;
#pragma unroll
  for (int c = 0; c < CC; c++){ float d = xv[c]-mu; var += d*d; }
  var *= (1.f/CC);
  float rs = rsqrtf(var + 1e-5f);
  float* xo = xout + (size_t)b*CC*NPIX + p;
  float* yo = y2 + (size_t)b*CC*NPIX + p;
#pragma unroll
  for (int c = 0; c < CC; c++){
    xo[(size_t)c*NPIX] = xv[c];
    yo[(size_t)c*NPIX] = (xv[c]-mu)*rs*ln2w[c] + ln2b[c];
  }
}

// ---------------- K_pool --------------------------------------------------------
__global__ __launch_bounds__(256) void k_pool(const float* __restrict__ y2, float* __restrict__ pooled)
{
  int bc = blockIdx.x;
  const float* r = y2 + (size_t)bc*NPIX;
  float s = 0.f;
  for (int n = threadIdx.x; n < NPIX; n += 256) s += r[n];
  s = wave_sum(s);
  __shared__ float red[4];
  int lane = threadIdx.x & 63, wv = threadIdx.x >> 6;
  if (lane == 0) red[wv] = s;
  __syncthreads();
  if (threadIdx.x == 0) pooled[bc] = (red[0]+red[1]+red[2]+red[3]) * (1.f/NPIX);
}

// ---------------- K6: MoE gate ---------------------------------------------------
__global__ __launch_bounds__(64) void k_moe_gate(
    const float* __restrict__ pooled, const float* __restrict__ text,
    const float* __restrict__ gwx, const float* __restrict__ gwt, float* __restrict__ gates)
{
  int tid = threadIdx.x;
  int b = tid >> 4, e = tid & 15;
  float acc = 0.f;
  for (int c = 0; c < CC; c++) acc += pooled[b*CC + c]*gwx[c*NE + e];
  for (int d = 0; d < TD; d++) acc += text[b*TD + d]*gwt[d*NE + e];
  __shared__ float lg[SB][NE];
  lg[b][e] = acc;
  __syncthreads();
  if (tid < SB){
    int bb = tid;
    float mx = -1e30f;
    for (int i = 0; i < NE; i++) mx = fmaxf(mx, lg[bb][i]);
    float ex[NE]; float s = 0.f;
    for (int i = 0; i < NE; i++){ ex[i] = __expf(lg[bb][i]-mx); s += ex[i]; }
    int i1 = 0; float p1 = -1.f;
    for (int i = 0; i < NE; i++) if (ex[i] > p1){ p1 = ex[i]; i1 = i; }
    int i2 = -1; float p2 = -1.f;
    for (int i = 0; i < NE; i++) if (i != i1 && ex[i] > p2){ p2 = ex[i]; i2 = i; }
    float denom = p1 + p2;
    for (int i = 0; i < NE; i++)
      gates[bb*NE + i] = (i == i1 || i == i2) ? ex[i]/denom : 0.f;
  }
}

// ================= Expert path ===================================================
// h slot sizes in floats: t0: 48*4096, t1: 48*16384, t2: 48*1024
__device__ __forceinline__ float* hslot(float* hb, int e, int b, int np, bool batched){
  if (batched){
    int t0c = (e+2)/3, t1c = (e+1)/3, t2c = e/3;
    size_t off = 4u*((size_t)t0c*196608u + (size_t)t1c*786432u + (size_t)t2c*49152u);
    return hb + off + (size_t)b*CC*np;
  }
  return hb + (size_t)b*CC*np;
}

// conv1 input fetch from y2 (64x64), type-transformed, zero-pad OOB in S-space
template<int TYPE, int S>
__device__ __forceinline__ void fetch_in(const float* __restrict__ yc, int oy, int ox, float* z){
#pragma unroll
  for (int ky = 0; ky < 3; ky++){
    int yy = oy + ky - 1;
#pragma unroll
    for (int kx = 0; kx < 3; kx++){
      int xx = ox + kx - 1;
      float v = 0.f;
      if ((unsigned)yy < (unsigned)S && (unsigned)xx < (unsigned)S){
        if (TYPE == 0) v = yc[yy*64 + xx];
        else if (TYPE == 1) v = yc[(yy>>1)*64 + (xx>>1)];
        else {
          int y0 = yy*2, x0 = xx*2;
          v = fmaxf(fmaxf(yc[y0*64+x0], yc[y0*64+x0+1]),
                    fmaxf(yc[(y0+1)*64+x0], yc[(y0+1)*64+x0+1]));
        }
      }
      z[ky*3+kx] = v;
    }
  }
}

template<int S>
__device__ __forceinline__ void fetch_h(const float* __restrict__ hc, int oy, int ox, float* z){
#pragma unroll
  for (int ky = 0; ky < 3; ky++){
    int yy = oy + ky - 1;
#pragma unroll
    for (int kx = 0; kx < 3; kx++){
      int xx = ox + kx - 1;
      z[ky*3+kx] = ((unsigned)yy < (unsigned)S && (unsigned)xx < (unsigned)S) ? hc[yy*S + xx] : 0.f;
    }
  }
}

// ---- conv1 (+bias+gelu): grid (tiles*4, SB, nexp_of_type | 1) -------------------
template<int TYPE>
__global__ __launch_bounds__(256) void k_econv1(
    const float* __restrict__ y2, const float* __restrict__ w1, const float* __restrict__ b1,
    const float* __restrict__ gates, float* __restrict__ hbase, int ebase)
{
  constexpr int S  = (TYPE==1) ? 128 : ((TYPE==2) ? 32 : 64);
  constexpr int NP = S*S;
  bool batched = (gridDim.z > 1);
  int e = batched ? (TYPE + 3*(int)blockIdx.z) : ebase;
  int b = blockIdx.y;
  if (gates[b*NE + e] == 0.f) return;
  int ocg = blockIdx.x & 3, tile = blockIdx.x >> 2;

  __shared__ float wl[5184];   // [(ic*9+k)*12 + j]
  const float* wg = w1 + (size_t)e*CC*CC*9;
  for (int i = threadIdx.x; i < 5184; i += 256){
    int ic = i/108, r = i%108, k = r/12, j = r%12;
    wl[i] = wg[(((ocg*12+j)*CC + ic)*9) + k];
  }
  __syncthreads();

  int px0 = tile*512 + threadIdx.x;
  int px1 = px0 + 256;
  int oy0 = px0/S, ox0 = px0%S, oy1 = px1/S, ox1 = px1%S;
  float acc0[12], acc1[12];
#pragma unroll
  for (int j = 0; j < 12; j++) acc0[j] = acc1[j] = b1[e*CC + ocg*12 + j];
  const float* yb = y2 + (size_t)b*CC*NPIX;
  for (int ic = 0; ic < CC; ic++){
    const float* yc = yb + (size_t)ic*NPIX;
    float z0[9], z1[9];
    fetch_in<TYPE,S>(yc, oy0, ox0, z0);
    fetch_in<TYPE,S>(yc, oy1, ox1, z1);
#pragma unroll
    for (int k = 0; k < 9; k++){
      const float* wr = &wl[(ic*9+k)*12];
      float a0 = z0[k], a1 = z1[k];
#pragma unroll
      for (int j = 0; j < 12; j++){ float w = wr[j]; acc0[j] += a0*w; acc1[j] += a1*w; }
    }
  }
  float* hp = hslot(hbase, e, b, NP, batched);
#pragma unroll
  for (int j = 0; j < 12; j++){
    int oc = ocg*12 + j;
    float t0 = acc0[j], t1 = acc1[j];
    hp[(size_t)oc*NP + px0] = 0.5f*t0*(1.f + erff(t0*0.70710678118654752f));
    hp[(size_t)oc*NP + px1] = 0.5f*t1*(1.f + erff(t1*0.70710678118654752f));
  }
}

__device__ __forceinline__ void bl_coord(int o, int& i0, int& i1, float& w0, float& w1){
  float f = 0.5f*o - 0.25f;
  float fl = floorf(f);
  int i = (int)fl;
  float fr = f - fl;
  i0 = i < 0 ? 0 : i;
  int j = i + 1;
  i1 = j > 31 ? 31 : j;
  w0 = 1.f - fr; w1 = fr;
}

// ---- conv2 (+bias) fused with {identity|maxpool|bilinear-up} + gate*atomicAdd ---
template<int TYPE>
__global__ __launch_bounds__(256) void k_econv2(
    const float* __restrict__ hbase_c, const float* __restrict__ w2, const float* __restrict__ b2,
    const float* __restrict__ gates, float* __restrict__ out, int ebase)
{
  constexpr int S  = (TYPE==1) ? 128 : ((TYPE==2) ? 32 : 64);
  constexpr int NP = S*S;
  constexpr int PX = (TYPE==2) ? 4 : 2;
  bool batched = (gridDim.z > 1);
  int e = batched ? (TYPE + 3*(int)blockIdx.z) : ebase;
  int b = blockIdx.y;
  float gt = gates[b*NE + e];
  if (gt == 0.f) return;
  int ocg = blockIdx.x & 3, tile = blockIdx.x >> 2;

  __shared__ float wl[5184];
  __shared__ float he[(TYPE==1) ? 512*13 : ((TYPE==2) ? 1024*13 : 13)];
  const float* wg = w2 + (size_t)e*CC*CC*9;
  for (int i = threadIdx.x; i < 5184; i += 256){
    int ic = i/108, r = i%108, k = r/12, j = r%12;
    wl[i] = wg[(((ocg*12+j)*CC + ic)*9) + k];
  }
  __syncthreads();

  const float* hp = hslot((float*)hbase_c, e, b, NP, batched);
  int base = tile*(256*PX);
  int pxl[PX], oyv[PX], oxv[PX];
#pragma unroll
  for (int i = 0; i < PX; i++){
    pxl[i] = base + threadIdx.x + 256*i;
    oyv[i] = pxl[i]/S; oxv[i] = pxl[i]%S;
  }
  float acc[PX][12];
#pragma unroll
  for (int i = 0; i < PX; i++)
#pragma unroll
    for (int j = 0; j < 12; j++) acc[i][j] = b2[e*CC + ocg*12 + j];

  for (int ic = 0; ic < CC; ic++){
    const float* hc = hp + (size_t)ic*NP;
    float z[PX][9];
#pragma unroll
    for (int i = 0; i < PX; i++) fetch_h<S>(hc, oyv[i], oxv[i], z[i]);
#pragma unroll
    for (int k = 0; k < 9; k++){
      const float* wr = &wl[(ic*9+k)*12];
#pragma unroll
      for (int i = 0; i < PX; i++){
        float a = z[i][k];
#pragma unroll
        for (int j = 0; j < 12; j++) acc[i][j] += a*wr[j];
      }
    }
  }

  float* ob = out + (size_t)b*CC*NPIX;
  if (TYPE == 0){
#pragma unroll
    for (int i = 0; i < PX; i++){
#pragma unroll
      for (int j = 0; j < 12; j++){
        int oc = ocg*12 + j;
        atomicAdd(&ob[(size_t)oc*NPIX + pxl[i]], gt*acc[i][j]);
      }
    }
  } else if (TYPE == 1){
    // block covers rows [4*tile, 4*tile+4) of the 128x128 pre-pool image
#pragma unroll
    for (int i = 0; i < PX; i++){
      int lp = threadIdx.x + 256*i;      // 0..511 local
#pragma unroll
      for (int j = 0; j < 12; j++) he[lp*13 + j] = acc[i][j];
    }
    __syncthreads();
    if (threadIdx.x < 128){
      int oyl = threadIdx.x >> 6;        // 0..1
      int ox  = threadIdx.x & 63;
      int gy  = tile*2 + oyl;            // pooled row
      int l0  = (oyl*2)*128 + 2*ox;
#pragma unroll
      for (int j = 0; j < 12; j++){
        float m = fmaxf(fmaxf(he[l0*13+j],       he[(l0+1)*13+j]),
                        fmaxf(he[(l0+128)*13+j], he[(l0+129)*13+j]));
        int oc = ocg*12 + j;
        atomicAdd(&ob[(size_t)oc*NPIX + gy*64 + ox], gt*m);
      }
    }
  } else {
    // whole 32x32 tile resident in LDS; bilinear-up to 64x64
#pragma unroll
    for (int i = 0; i < PX; i++){
      int lp = threadIdx.x + 256*i;      // 0..1023
#pragma unroll
      for (int j = 0; j < 12; j++) he[lp*13 + j] = acc[i][j];
    }
    __syncthreads();
    for (int it = 0; it < 16; it++){
      int op = threadIdx.x + 256*it;     // 0..4095
      int y = op >> 6, x = op & 63;
      int y0,y1,x0,x1; float wy0,wy1,wx0,wx1;
      bl_coord(y, y0, y1, wy0, wy1);
      bl_coord(x, x0, x1, wx0, wx1);
#pragma unroll
      for (int j = 0; j < 12; j++){
        float v = wy0*(wx0*he[(y0*32+x0)*13+j] + wx1*he[(y0*32+x1)*13+j])
                + wy1*(wx0*he[(y1*32+x0)*13+j] + wx1*he[(y1*32+x1)*13+j]);
        int oc = ocg*12 + j;
        atomicAdd(&ob[(size_t)oc*NPIX + op], gt*v);
      }
    }
  }
}

// ---------------- launch ---------------------------------------------------------
extern "C" void kernel_launch(void* const* d_in, const int* in_sizes, int n_in,
                              void* d_out, int out_size, void* d_ws, size_t ws_size,
                              hipStream_t stream) {
  const float* x      = (const float*)d_in[0];
  const float* text   = (const float*)d_in[1];
  const float* ln1w   = (const float*)d_in[3];
  const float* ln1b   = (const float*)d_in[4];
  const float* ln2w   = (const float*)d_in[5];
  const float* ln2b   = (const float*)d_in[6];
  const float* qkvw   = (const float*)d_in[7];
  const float* qkvdw  = (const float*)d_in[8];
  const float* projw  = (const float*)d_in[9];
  const float* routw  = (const float*)d_in[10];
  const float* gwx    = (const float*)d_in[11];
  const float* gwt    = (const float*)d_in[12];
  const float* ew1    = (const float*)d_in[13];
  const float* eb1    = (const float*)d_in[14];
  const float* ew2    = (const float*)d_in[15];
  const float* eb2    = (const float*)d_in[16];
  float* out = (float*)d_out;

  float* wsf = (float*)d_ws;
  float* y2      = wsf;                      // 786432 f
  float* pooled  = wsf + 786432;             // 192
  float* gates   = wsf + 786624;             // 64
  float* F       = wsf + 786944;             // front region / h region (aliased)
  float* qkv_raw = F;                        // 2359296
  float* qkv_dw  = F + 2359296;              // 2359296
  float* rl      = F + 4718592;              // 131072
  float* gmask   = F + 4849664;              // 131072
  float* attnout = F + 4980736;              // 786432  (F total 5767168 f)
  float* hbase   = F;                        // experts start after attention is done

  // batched mode needs (786944 + 21430272) floats = 88,868,864 B
  bool batched = ws_size >= (size_t)(786944 + 21430272)*sizeof(float);

  k_ln_qkv_router<<<dim3(16, SB), 256, 0, stream>>>(x, ln1w, ln1b, qkvw, routw, qkv_raw, rl);
  k_dwconv<<<dim3(16, 144, SB), 256, 0, stream>>>(qkv_raw, qkvdw, qkv_dw);
  k_router_gates<<<dim3(64), 256, 0, stream>>>(rl, gmask);
  k_attn<<<dim3(NH, SB), 256, 0, stream>>>(qkv_dw, gmask, attnout);
  k_proj_ln2<<<dim3(16, SB), 256, 0, stream>>>(attnout, x, projw, ln2w, ln2b, out, y2);
  k_pool<<<dim3(SB*CC), 256, 0, stream>>>(y2, pooled);
  k_moe_gate<<<dim3(1), 64, 0, stream>>>(pooled, text, gwx, gwt, gates);

  if (batched){
    k_econv1<0><<<dim3(32,  SB, 6), 256, 0, stream>>>(y2, ew1, eb1, gates, hbase, 0);
    k_econv1<1><<<dim3(128, SB, 5), 256, 0, stream>>>(y2, ew1, eb1, gates, hbase, 0);
    k_econv1<2><<<dim3(8,   SB, 5), 256, 0, stream>>>(y2, ew1, eb1, gates, hbase, 0);
    k_econv2<0><<<dim3(32,  SB, 6), 256, 0, stream>>>(hbase, ew2, eb2, gates, out, 0);
    k_econv2<1><<<dim3(128, SB, 5), 256, 0, stream>>>(hbase, ew2, eb2, gates, out, 0);
    k_econv2<2><<<dim3(4,   SB, 5), 256, 0, stream>>>(hbase, ew2, eb2, gates, out, 0);
  } else {
    for (int e = 0; e < NE; e++){
      int t = e % 3;
      if (t == 0){
        k_econv1<0><<<dim3(32,  SB, 1), 256, 0, stream>>>(y2, ew1, eb1, gates, hbase, e);
        k_econv2<0><<<dim3(32,  SB, 1), 256, 0, stream>>>(hbase, ew2, eb2, gates, out, e);
      } else if (t == 1){
        k_econv1<1><<<dim3(128, SB, 1), 256, 0, stream>>>(y2, ew1, eb1, gates, hbase, e);
        k_econv2<1><<<dim3(128, SB, 1), 256, 0, stream>>>(hbase, ew2, eb2, gates, out, e);
      } else {
        k_econv1<2><<<dim3(8,   SB, 1), 256, 0, stream>>>(y2, ew1, eb1, gates, hbase, e);
        k_econv2<2><<<dim3(4,   SB, 1), 256, 0, stream>>>(hbase, ew2, eb2, gates, out, e);
      }
    }
  }
  (void)in_sizes; (void)n_in; (void)out_size;
}

// Round 7
// 590.581 us; speedup vs baseline: 2.0536x; 1.0658x over previous
//
#include <hip/hip_runtime.h>
#include <math.h>

#define SB 4
#define CC 48
#define NH 8
#define HDIM 6
#define NPIX 4096
#define NE 16
#define TD 512

__device__ __forceinline__ float wave_sum(float t){
#pragma unroll
  for (int o = 32; o >= 1; o >>= 1) t += __shfl_xor(t, o, 64);
  return t;
}

__device__ __forceinline__ float gelu(float t){
  return 0.5f*t*(1.f + erff(t*0.70710678118654752f));
}

// acc[12] += z * w-row (3 float4 in scope: _w0,_w1,_w2)
#define ACC12(A, Z) { float _z=(Z); \
  A[0]+=_z*_w0.x; A[1]+=_z*_w0.y; A[2]+=_z*_w0.z; A[3]+=_z*_w0.w; \
  A[4]+=_z*_w1.x; A[5]+=_z*_w1.y; A[6]+=_z*_w1.z; A[7]+=_z*_w1.w; \
  A[8]+=_z*_w2.x; A[9]+=_z*_w2.y; A[10]+=_z*_w2.z; A[11]+=_z*_w2.w; }

// ---------------- K1: LN1 + qkv/router 1x1, 6 oc-sections ------------------------
__global__ __launch_bounds__(256) void k_ln_qkv(
    const float* __restrict__ x, const float* __restrict__ ln1w, const float* __restrict__ ln1b,
    const float* __restrict__ qkvw, const float* __restrict__ routw,
    float* __restrict__ qkv_raw, float* __restrict__ rl)
{
  int sec = blockIdx.z;
  int NOC = (sec == 5) ? 32 : 24;
  __shared__ __align__(16) float wl[32*48];
  int tid = threadIdx.x;
  for (int i = tid; i < NOC*48; i += 256){
    int oc = i/48, c = i%48, og = sec*24 + oc;
    wl[i] = (og < 144) ? qkvw[og*48 + c] : routw[(og-144)*48 + c];
  }
  __syncthreads();
  int b = blockIdx.y;
  int p0 = blockIdx.x*512 + tid, p1 = p0 + 256;
  const float* xb = x + (size_t)b*CC*NPIX;
  float v0[48], v1[48];
  float mu0 = 0.f, mu1 = 0.f;
#pragma unroll
  for (int c = 0; c < CC; c++){
    v0[c] = xb[(size_t)c*NPIX + p0]; v1[c] = xb[(size_t)c*NPIX + p1];
    mu0 += v0[c]; mu1 += v1[c];
  }
  mu0 *= (1.f/CC); mu1 *= (1.f/CC);
  float va0 = 0.f, va1 = 0.f;
#pragma unroll
  for (int c = 0; c < CC; c++){
    float d0 = v0[c]-mu0, d1 = v1[c]-mu1; va0 += d0*d0; va1 += d1*d1;
  }
  float rs0 = rsqrtf(va0*(1.f/CC) + 1e-5f), rs1 = rsqrtf(va1*(1.f/CC) + 1e-5f);
#pragma unroll
  for (int c = 0; c < CC; c++){
    float w = ln1w[c], bb = ln1b[c];
    v0[c] = (v0[c]-mu0)*rs0*w + bb;
    v1[c] = (v1[c]-mu1)*rs1*w + bb;
  }
  float* qb = qkv_raw + (size_t)b*144*NPIX;
  float* rb = rl + (size_t)b*NH*NPIX;
  for (int oc = 0; oc < NOC; oc++){
    const float4* wv = (const float4*)&wl[oc*48];
    float s0 = 0.f, s1 = 0.f;
#pragma unroll
    for (int q = 0; q < 12; q++){
      float4 w = wv[q];
      s0 += w.x*v0[q*4] + w.y*v0[q*4+1] + w.z*v0[q*4+2] + w.w*v0[q*4+3];
      s1 += w.x*v1[q*4] + w.y*v1[q*4+1] + w.z*v1[q*4+2] + w.w*v1[q*4+3];
    }
    int og = sec*24 + oc;
    float* dst = (og < 144) ? (qb + (size_t)og*NPIX) : (rb + (size_t)(og-144)*NPIX);
    dst[p0] = s0; dst[p1] = s1;
  }
}

// ---------------- K2: depthwise 3x3, pad 1 --------------------------------------
__global__ __launch_bounds__(256) void k_dwconv(
    const float* __restrict__ in, const float* __restrict__ w, float* __restrict__ out)
{
  int ch = blockIdx.y, b = blockIdx.z;
  int p = blockIdx.x*256 + threadIdx.x;
  int y = p >> 6, xx = p & 63;
  const float* wc = w + ch*9;
  const float* ib = in + ((size_t)b*144 + ch)*NPIX;
  float acc = 0.f;
#pragma unroll
  for (int ky = 0; ky < 3; ky++){
    int yy = y + ky - 1;
    if ((unsigned)yy < 64u){
#pragma unroll
      for (int kx = 0; kx < 3; kx++){
        int xc = xx + kx - 1;
        if ((unsigned)xc < 64u) acc += wc[ky*3+kx]*ib[yy*64+xc];
      }
    }
  }
  out[((size_t)b*144 + ch)*NPIX + p] = acc;
}

// ---------------- K3: per-pixel head routing ------------------------------------
__global__ __launch_bounds__(256) void k_router_gates(
    const float* __restrict__ rl, float* __restrict__ g)
{
  int idx = blockIdx.x*256 + threadIdx.x;
  int b = idx >> 12, p = idx & (NPIX-1);
  const float* r = rl + (size_t)b*NH*NPIX + p;
  float l[NH];
  float mx = -1e30f;
#pragma unroll
  for (int h = 0; h < NH; h++){ l[h] = r[(size_t)h*NPIX]; mx = fmaxf(mx, l[h]); }
  float s = 0.f;
#pragma unroll
  for (int h = 0; h < NH; h++){ l[h] = __expf(l[h]-mx); s += l[h]; }
  int i1 = 0; float p1 = -1.f;
#pragma unroll
  for (int h = 0; h < NH; h++) if (l[h] > p1){ p1 = l[h]; i1 = h; }
  int i2 = -1; float p2 = -1.f;
#pragma unroll
  for (int h = 0; h < NH; h++) if (h != i1 && l[h] > p2){ p2 = l[h]; i2 = h; }
  float denom = p1 + p2;
  float* go = g + (size_t)b*NH*NPIX + p;
#pragma unroll
  for (int h = 0; h < NH; h++)
    go[(size_t)h*NPIX] = (h == i1 || h == i2) ? l[h]/denom : 0.f;
}

// ---------------- attention phase A: partial gram/norm sums ---------------------
__global__ __launch_bounds__(256) void k_attn_part(
    const float* __restrict__ qkv, float* __restrict__ part)
{
  int ch = blockIdx.x, h = blockIdx.y, b = blockIdx.z;
  const float* q = qkv + ((size_t)b*144 + h*HDIM)*NPIX;
  const float* k = qkv + ((size_t)b*144 + 48 + h*HDIM)*NPIX;
  int tid = threadIdx.x;
  float qq[HDIM] = {0}, kk[HDIM] = {0}, qk[HDIM*HDIM] = {0};
#pragma unroll
  for (int t = 0; t < 2; t++){
    int n = ch*512 + t*256 + tid;
    float qv[HDIM], kv[HDIM];
#pragma unroll
    for (int c = 0; c < HDIM; c++){ qv[c] = q[(size_t)c*NPIX + n]; kv[c] = k[(size_t)c*NPIX + n]; }
#pragma unroll
    for (int c = 0; c < HDIM; c++){
      qq[c] += qv[c]*qv[c]; kk[c] += kv[c]*kv[c];
#pragma unroll
      for (int d = 0; d < HDIM; d++) qk[c*HDIM+d] += qv[c]*kv[d];
    }
  }
#pragma unroll
  for (int c = 0; c < HDIM; c++){ qq[c] = wave_sum(qq[c]); kk[c] = wave_sum(kk[c]); }
#pragma unroll
  for (int i = 0; i < HDIM*HDIM; i++) qk[i] = wave_sum(qk[i]);
  __shared__ float red[4][48];
  int lane = tid & 63, wv = tid >> 6;
  if (lane == 0){
#pragma unroll
    for (int c = 0; c < HDIM; c++){ red[wv][c] = qq[c]; red[wv][6+c] = kk[c]; }
#pragma unroll
    for (int i = 0; i < HDIM*HDIM; i++) red[wv][12+i] = qk[i];
  }
  __syncthreads();
  if (tid < 48)
    part[((size_t)(b*NH+h)*8 + ch)*48 + tid] = red[0][tid]+red[1][tid]+red[2][tid]+red[3][tid];
}

// ---------------- attention phase B: softmax matrix -----------------------------
__global__ __launch_bounds__(64) void k_attn_soft(
    const float* __restrict__ part, float* __restrict__ smg)
{
  int h = blockIdx.x, b = blockIdx.y, tid = threadIdx.x;
  __shared__ float tot[48];
  if (tid < 48){
    float s = 0.f;
    for (int ch = 0; ch < 8; ch++) s += part[((size_t)(b*NH+h)*8 + ch)*48 + tid];
    tot[tid] = s;
  }
  __syncthreads();
  if (tid < HDIM){
    int c = tid;
    float qn = fmaxf(sqrtf(tot[c]), 1e-12f);
    float row[HDIM];
    float mx = -1e30f;
#pragma unroll
    for (int d = 0; d < HDIM; d++){
      float kn = fmaxf(sqrtf(tot[6+d]), 1e-12f);
      float a = tot[12 + c*HDIM + d] / (qn*kn) * 0.40824829046386307f;
      row[d] = a; mx = fmaxf(mx, a);
    }
    float s = 0.f;
#pragma unroll
    for (int d = 0; d < HDIM; d++){ row[d] = __expf(row[d]-mx); s += row[d]; }
#pragma unroll
    for (int d = 0; d < HDIM; d++) smg[(size_t)(b*NH+h)*36 + c*HDIM + d] = row[d]/s;
  }
}

// ---------------- attention phase C: apply sm·v × gate --------------------------
__global__ __launch_bounds__(256) void k_attn_apply(
    const float* __restrict__ qkv, const float* __restrict__ smg,
    const float* __restrict__ g, float* __restrict__ out)
{
  int h = blockIdx.y, b = blockIdx.z;
  __shared__ float sm[36];
  int tid = threadIdx.x;
  if (tid < 36) sm[tid] = smg[(size_t)(b*NH+h)*36 + tid];
  __syncthreads();
  int n = blockIdx.x*256 + tid;
  const float* v = qkv + ((size_t)b*144 + 96 + h*HDIM)*NPIX;
  float vv[HDIM];
#pragma unroll
  for (int d = 0; d < HDIM; d++) vv[d] = v[(size_t)d*NPIX + n];
  float gg = g[((size_t)b*NH + h)*NPIX + n];
  float* ob = out + ((size_t)b*CC + h*HDIM)*NPIX;
#pragma unroll
  for (int c = 0; c < HDIM; c++){
    float o = 0.f;
#pragma unroll
    for (int d = 0; d < HDIM; d++) o += sm[c*HDIM+d]*vv[d];
    ob[(size_t)c*NPIX + n] = o*gg;
  }
}

// ---------------- K5: proj 1x1 + residual + LN2 ----------------------------------
__global__ __launch_bounds__(256) void k_proj_ln2(
    const float* __restrict__ attn_out, const float* __restrict__ x,
    const float* __restrict__ projw, const float* __restrict__ ln2w, const float* __restrict__ ln2b,
    float* __restrict__ xout, float* __restrict__ y2)
{
  __shared__ __align__(16) float w[CC*CC];
  int tid = threadIdx.x;
  for (int i = tid; i < CC*CC; i += 256) w[i] = projw[i];
  __syncthreads();
  int b = blockIdx.y;
  int p = blockIdx.x*256 + tid;
  const float* ain = attn_out + (size_t)b*CC*NPIX + p;
  float a[CC];
#pragma unroll
  for (int c = 0; c < CC; c++) a[c] = ain[(size_t)c*NPIX];
  const float* xb = x + (size_t)b*CC*NPIX + p;
  float xv[CC];
  float mu = 0.f;
#pragma unroll
  for (int oc = 0; oc < CC; oc++){
    const float4* wr = (const float4*)&w[oc*CC];
    float acc = 0.f;
#pragma unroll
    for (int q = 0; q < 12; q++){
      float4 ww = wr[q];
      acc += ww.x*a[q*4] + ww.y*a[q*4+1] + ww.z*a[q*4+2] + ww.w*a[q*4+3];
    }
    float t = xb[(size_t)oc*NPIX] + acc;
    xv[oc] = t; mu += t;
  }
  mu *= (1.f/CC);
  float var = 0.f;
#pragma unroll
  for (int c = 0; c < CC; c++){ float d = xv[c]-mu; var += d*d; }
  var *= (1.f/CC);
  float rs = rsqrtf(var + 1e-5f);
  float* xo = xout + (size_t)b*CC*NPIX + p;
  float* yo = y2 + (size_t)b*CC*NPIX + p;
#pragma unroll
  for (int c = 0; c < CC; c++){
    xo[(size_t)c*NPIX] = xv[c];
    yo[(size_t)c*NPIX] = (xv[c]-mu)*rs*ln2w[c] + ln2b[c];
  }
}

// ---------------- K_pool --------------------------------------------------------
__global__ __launch_bounds__(256) void k_pool(const float* __restrict__ y2, float* __restrict__ pooled)
{
  int bc = blockIdx.x;
  const float* r = y2 + (size_t)bc*NPIX;
  float s = 0.f;
  for (int n = threadIdx.x; n < NPIX; n += 256) s += r[n];
  s = wave_sum(s);
  __shared__ float red[4];
  int lane = threadIdx.x & 63, wv = threadIdx.x >> 6;
  if (lane == 0) red[wv] = s;
  __syncthreads();
  if (threadIdx.x == 0) pooled[bc] = (red[0]+red[1]+red[2]+red[3]) * (1.f/NPIX);
}

// ---------------- K6: MoE gate ---------------------------------------------------
__global__ __launch_bounds__(64) void k_moe_gate(
    const float* __restrict__ pooled, const float* __restrict__ text,
    const float* __restrict__ gwx, const float* __restrict__ gwt, float* __restrict__ gates)
{
  int tid = threadIdx.x;
  int b = tid >> 4, e = tid & 15;
  float acc = 0.f;
  for (int c = 0; c < CC; c++) acc += pooled[b*CC + c]*gwx[c*NE + e];
  for (int d = 0; d < TD; d++) acc += text[b*TD + d]*gwt[d*NE + e];
  __shared__ float lg[SB][NE];
  lg[b][e] = acc;
  __syncthreads();
  if (tid < SB){
    int bb = tid;
    float mx = -1e30f;
    for (int i = 0; i < NE; i++) mx = fmaxf(mx, lg[bb][i]);
    float ex[NE]; float s = 0.f;
    for (int i = 0; i < NE; i++){ ex[i] = __expf(lg[bb][i]-mx); s += ex[i]; }
    int i1 = 0; float p1 = -1.f;
    for (int i = 0; i < NE; i++) if (ex[i] > p1){ p1 = ex[i]; i1 = i; }
    int i2 = -1; float p2 = -1.f;
    for (int i = 0; i < NE; i++) if (i != i1 && ex[i] > p2){ p2 = ex[i]; i2 = i; }
    float denom = p1 + p2;
    for (int i = 0; i < NE; i++)
      gates[bb*NE + i] = (i == i1 || i == i2) ? ex[i]/denom : 0.f;
  }
}

// ================= Expert path (batched h-slot packing) ==========================
__device__ __forceinline__ float* hslot(float* hb, int e, int b, int np){
  int t0c = (e+2)/3, t1c = (e+1)/3, t2c = e/3;
  size_t off = 4u*((size_t)t0c*196608u + (size_t)t1c*786432u + (size_t)t2c*49152u);
  return hb + off + (size_t)b*CC*np;
}

// ---- unified conv1 (+bias+gelu): grid (64, SB, NE) ------------------------------
__global__ __launch_bounds__(256) void k_econv1u(
    const float* __restrict__ y2, const float* __restrict__ w1, const float* __restrict__ b1,
    const float* __restrict__ gates, float* __restrict__ hbase)
{
  int e = blockIdx.z, ty = e % 3;
  int nx = (ty == 0) ? 32 : ((ty == 1) ? 64 : 16);
  if ((int)blockIdx.x >= nx) return;
  int b = blockIdx.y;
  if (gates[b*NE + e] == 0.f) return;
  int ocg = blockIdx.x & 3, band = blockIdx.x >> 2, yb = band*8;
  int tid = threadIdx.x;

  __shared__ __align__(16) float smem[5184 + 5200];
  float* wl = smem; float* patch = smem + 5184;
  const float* wg = w1 + (size_t)e*CC*CC*9 + (size_t)(ocg*12)*CC*9;
  for (int i = tid; i < 5184; i += 256){
    int ic = i/108, r2 = i%108, k = r2/12, j = r2%12;
    wl[i] = wg[((size_t)j*CC + ic)*9 + k];
  }
  float bb[12];
#pragma unroll
  for (int j = 0; j < 12; j++) bb[j] = b1[e*CC + ocg*12 + j];
  const float* yb2 = y2 + (size_t)b*CC*NPIX;

  if (ty == 0){
    float* hp = hslot(hbase, e, b, 4096);
    int r = tid >> 5, xp = (tid & 31)*2;
    float a0[12], a1[12];
#pragma unroll
    for (int j = 0; j < 12; j++){ a0[j] = bb[j]; a1[j] = bb[j]; }
    for (int icg = 0; icg < 12; icg++){
      __syncthreads();
      for (int i = tid; i < 2560; i += 256){
        int icl = i/640, rem = i%640, rr = rem>>6, cc = rem&63;
        int s = yb - 1 + rr;
        patch[icl*650 + rr*65 + cc] = ((unsigned)s < 64u) ? yb2[(size_t)(icg*4+icl)*NPIX + s*64 + cc] : 0.f;
      }
      __syncthreads();
#pragma unroll
      for (int icl = 0; icl < 4; icl++){
        const float* pp = patch + icl*650 + r*65;
        float zz[3][4];
#pragma unroll
        for (int dy = 0; dy < 3; dy++)
#pragma unroll
          for (int dx = 0; dx < 4; dx++){
            int xx = xp - 1 + dx;
            zz[dy][dx] = ((unsigned)xx < 64u) ? pp[dy*65 + xx] : 0.f;
          }
        const float4* wv = (const float4*)(wl + (icg*4+icl)*108);
#pragma unroll
        for (int k = 0; k < 9; k++){
          int ky = k/3, kx = k%3;
          float4 _w0 = wv[k*3], _w1 = wv[k*3+1], _w2 = wv[k*3+2];
          ACC12(a0, zz[ky][kx]);
          ACC12(a1, zz[ky][kx+1]);
        }
      }
    }
    int p0 = (yb + r)*64 + xp;
#pragma unroll
    for (int j = 0; j < 12; j++){
      int oc = ocg*12 + j;
      hp[(size_t)oc*4096 + p0]     = gelu(a0[j]);
      hp[(size_t)oc*4096 + p0 + 1] = gelu(a1[j]);
    }
  } else if (ty == 1){
    float* hp = hslot(hbase, e, b, 16384);
    int r = tid >> 5, xp = (tid & 31)*4;
    float ac[4][12];
#pragma unroll
    for (int i = 0; i < 4; i++)
#pragma unroll
      for (int j = 0; j < 12; j++) ac[i][j] = bb[j];
    int row0 = (yb >> 1) - 1;
    for (int icg = 0; icg < 12; icg++){
      __syncthreads();
      for (int i = tid; i < 1536; i += 256){
        int icl = i/384, rem = i%384, rr = rem>>6, cc = rem&63;
        int s = row0 + rr;
        patch[icl*390 + rr*65 + cc] = ((unsigned)s < 64u) ? yb2[(size_t)(icg*4+icl)*NPIX + s*64 + cc] : 0.f;
      }
      __syncthreads();
#pragma unroll
      for (int icl = 0; icl < 4; icl++){
        const float* pp = patch + icl*390;
        int lr[3];
#pragma unroll
        for (int dy = 0; dy < 3; dy++) lr[dy] = ((r + dy - 1) >> 1) + 1;
        float zz[3][6];
#pragma unroll
        for (int dy = 0; dy < 3; dy++)
#pragma unroll
          for (int dx = 0; dx < 6; dx++){
            int xx = xp - 1 + dx;
            zz[dy][dx] = ((unsigned)xx < 128u) ? pp[lr[dy]*65 + (xx>>1)] : 0.f;
          }
        const float4* wv = (const float4*)(wl + (icg*4+icl)*108);
#pragma unroll
        for (int k = 0; k < 9; k++){
          int ky = k/3, kx = k%3;
          float4 _w0 = wv[k*3], _w1 = wv[k*3+1], _w2 = wv[k*3+2];
          ACC12(ac[0], zz[ky][kx]);
          ACC12(ac[1], zz[ky][kx+1]);
          ACC12(ac[2], zz[ky][kx+2]);
          ACC12(ac[3], zz[ky][kx+3]);
        }
      }
    }
#pragma unroll
    for (int i = 0; i < 4; i++){
      int p = (yb + r)*128 + xp + i;
#pragma unroll
      for (int j = 0; j < 12; j++)
        hp[(size_t)(ocg*12 + j)*16384 + p] = gelu(ac[i][j]);
    }
  } else {
    float* hp = hslot(hbase, e, b, 1024);
    int r = tid >> 5, xp = tid & 31;
    float ac[12];
#pragma unroll
    for (int j = 0; j < 12; j++) ac[j] = bb[j];
    int row0 = 2*yb - 2;
    for (int icg = 0; icg < 12; icg++){
      __syncthreads();
      for (int i = tid; i < 5120; i += 256){
        int icl = i/1280, rem = i%1280, rr = rem>>6, cc = rem&63;
        int s = row0 + rr;
        patch[icl*1300 + rr*65 + cc] = ((unsigned)s < 64u) ? yb2[(size_t)(icg*4+icl)*NPIX + s*64 + cc] : 0.f;
      }
      __syncthreads();
#pragma unroll
      for (int icl = 0; icl < 4; icl++){
        const float* pp = patch + icl*1300;
        float zz[3][3];
#pragma unroll
        for (int dy = 0; dy < 3; dy++){
          int sy = yb + r + dy - 1;
          int pr = 2*(r + dy - 1) + 2;
#pragma unroll
          for (int dx = 0; dx < 3; dx++){
            int sx = xp + dx - 1;
            float m = 0.f;
            if ((unsigned)sy < 32u && (unsigned)sx < 32u){
              int c2 = 2*sx;
              m = fmaxf(fmaxf(pp[pr*65+c2], pp[pr*65+c2+1]),
                        fmaxf(pp[(pr+1)*65+c2], pp[(pr+1)*65+c2+1]));
            }
            zz[dy][dx] = m;
          }
        }
        const float4* wv = (const float4*)(wl + (icg*4+icl)*108);
#pragma unroll
        for (int k = 0; k < 9; k++){
          int ky = k/3, kx = k%3;
          float4 _w0 = wv[k*3], _w1 = wv[k*3+1], _w2 = wv[k*3+2];
          ACC12(ac, zz[ky][kx]);
        }
      }
    }
    int p = (yb + r)*32 + xp;
#pragma unroll
    for (int j = 0; j < 12; j++)
      hp[(size_t)(ocg*12 + j)*1024 + p] = gelu(ac[j]);
  }
}

// ---- unified conv2 (+bias, fused tail) for types 0,1: grid (64, SB, NE) ---------
__global__ __launch_bounds__(256) void k_econv2u(
    const float* __restrict__ hbase, const float* __restrict__ w2, const float* __restrict__ b2,
    const float* __restrict__ gates, float* __restrict__ out)
{
  int e = blockIdx.z, ty = e % 3;
  if (ty == 2) return;
  int nx = (ty == 0) ? 32 : 64;
  if ((int)blockIdx.x >= nx) return;
  int b = blockIdx.y;
  float gt = gates[b*NE + e];
  if (gt == 0.f) return;
  int ocg = blockIdx.x & 3, band = blockIdx.x >> 2, yb = band*8;
  int tid = threadIdx.x;

  __shared__ __align__(16) float smem[5184 + 5200];
  float* wl = smem; float* patch = smem + 5184;
  const float* wg = w2 + (size_t)e*CC*CC*9 + (size_t)(ocg*12)*CC*9;
  for (int i = tid; i < 5184; i += 256){
    int ic = i/108, r2 = i%108, k = r2/12, j = r2%12;
    wl[i] = wg[((size_t)j*CC + ic)*9 + k];
  }
  float bb[12];
#pragma unroll
  for (int j = 0; j < 12; j++) bb[j] = b2[e*CC + ocg*12 + j];
  float* ob = out + (size_t)b*CC*NPIX;

  if (ty == 0){
    const float* hp = hslot((float*)hbase, e, b, 4096);
    int r = tid >> 5, xp = (tid & 31)*2;
    float a0[12], a1[12];
#pragma unroll
    for (int j = 0; j < 12; j++){ a0[j] = bb[j]; a1[j] = bb[j]; }
    for (int icg = 0; icg < 12; icg++){
      __syncthreads();
      for (int i = tid; i < 2560; i += 256){
        int icl = i/640, rem = i%640, rr = rem>>6, cc = rem&63;
        int s = yb - 1 + rr;
        patch[icl*650 + rr*65 + cc] = ((unsigned)s < 64u) ? hp[(size_t)(icg*4+icl)*4096 + s*64 + cc] : 0.f;
      }
      __syncthreads();
#pragma unroll
      for (int icl = 0; icl < 4; icl++){
        const float* pp = patch + icl*650 + r*65;
        float zz[3][4];
#pragma unroll
        for (int dy = 0; dy < 3; dy++)
#pragma unroll
          for (int dx = 0; dx < 4; dx++){
            int xx = xp - 1 + dx;
            zz[dy][dx] = ((unsigned)xx < 64u) ? pp[dy*65 + xx] : 0.f;
          }
        const float4* wv = (const float4*)(wl + (icg*4+icl)*108);
#pragma unroll
        for (int k = 0; k < 9; k++){
          int ky = k/3, kx = k%3;
          float4 _w0 = wv[k*3], _w1 = wv[k*3+1], _w2 = wv[k*3+2];
          ACC12(a0, zz[ky][kx]);
          ACC12(a1, zz[ky][kx+1]);
        }
      }
    }
    int p0 = (yb + r)*64 + xp;
#pragma unroll
    for (int j = 0; j < 12; j++){
      int oc = ocg*12 + j;
      atomicAdd(&ob[(size_t)oc*4096 + p0],     gt*a0[j]);
      atomicAdd(&ob[(size_t)oc*4096 + p0 + 1], gt*a1[j]);
    }
  } else {
    const float* hp = hslot((float*)hbase, e, b, 16384);
    int r = tid >> 5, xp = (tid & 31)*4;
    float ac[4][12];
#pragma unroll
    for (int i = 0; i < 4; i++)
#pragma unroll
      for (int j = 0; j < 12; j++) ac[i][j] = bb[j];
    for (int icg = 0; icg < 12; icg++){
      __syncthreads();
      for (int i = tid; i < 5120; i += 256){
        int icl = i/1280, rem = i%1280, rr = rem>>7, cc = rem&127;
        int s = yb - 1 + rr;
        patch[icl*1290 + rr*129 + cc] = ((unsigned)s < 128u) ? hp[(size_t)(icg*4+icl)*16384 + s*128 + cc] : 0.f;
      }
      __syncthreads();
#pragma unroll
      for (int icl = 0; icl < 4; icl++){
        const float* pp = patch + icl*1290 + r*129;
        float zz[3][6];
#pragma unroll
        for (int dy = 0; dy < 3; dy++)
#pragma unroll
          for (int dx = 0; dx < 6; dx++){
            int xx = xp - 1 + dx;
            zz[dy][dx] = ((unsigned)xx < 128u) ? pp[dy*129 + xx] : 0.f;
          }
        const float4* wv = (const float4*)(wl + (icg*4+icl)*108);
#pragma unroll
        for (int k = 0; k < 9; k++){
          int ky = k/3, kx = k%3;
          float4 _w0 = wv[k*3], _w1 = wv[k*3+1], _w2 = wv[k*3+2];
          ACC12(ac[0], zz[ky][kx]);
          ACC12(ac[1], zz[ky][kx+1]);
          ACC12(ac[2], zz[ky][kx+2]);
          ACC12(ac[3], zz[ky][kx+3]);
        }
      }
    }
    // fused 2x2 maxpool: horizontal in-reg, vertical via shfl_xor(32) (rows r, r^1)
    int pr = (yb + r) >> 1;
    int c0 = xp >> 1;
#pragma unroll
    for (int j = 0; j < 12; j++){
      float m0 = fmaxf(ac[0][j], ac[1][j]);
      float m1 = fmaxf(ac[2][j], ac[3][j]);
      float o0 = fmaxf(m0, __shfl_xor(m0, 32, 64));
      float o1 = fmaxf(m1, __shfl_xor(m1, 32, 64));
      if ((r & 1) == 0){
        int oc = ocg*12 + j;
        atomicAdd(&ob[(size_t)oc*4096 + pr*64 + c0],     gt*o0);
        atomicAdd(&ob[(size_t)oc*4096 + pr*64 + c0 + 1], gt*o1);
      }
    }
  }
}

// ---- legacy type-2 conv2 (whole 32x32 in-block, bilinear-up fused) --------------
__device__ __forceinline__ void bl_coord(int o, int& i0, int& i1, float& w0, float& w1){
  float f = 0.5f*o - 0.25f;
  float fl = floorf(f);
  int i = (int)fl;
  float fr = f - fl;
  i0 = i < 0 ? 0 : i;
  int j = i + 1;
  i1 = j > 31 ? 31 : j;
  w0 = 1.f - fr; w1 = fr;
}

__global__ __launch_bounds__(256) void k_econv2t2(
    const float* __restrict__ hbase, const float* __restrict__ w2, const float* __restrict__ b2,
    const float* __restrict__ gates, float* __restrict__ out)
{
  constexpr int S = 32, NP = 1024, PX = 4;
  int e = 2 + 3*(int)blockIdx.z;
  int b = blockIdx.y;
  float gt = gates[b*NE + e];
  if (gt == 0.f) return;
  int ocg = blockIdx.x & 3;

  __shared__ float wl[5184];
  __shared__ float he[1024*13];
  const float* wg = w2 + (size_t)e*CC*CC*9;
  for (int i = threadIdx.x; i < 5184; i += 256){
    int oc = i / (CC*9); int r = i % (CC*9);
    wl[r*12 + oc] = wg[(size_t)(ocg*12 + oc)*CC*9 + r];
  }
  __syncthreads();

  const float* hp = hslot((float*)hbase, e, b, NP);
  int pxl[PX], oyv[PX], oxv[PX];
#pragma unroll
  for (int i = 0; i < PX; i++){
    pxl[i] = threadIdx.x + 256*i;
    oyv[i] = pxl[i]/S; oxv[i] = pxl[i]%S;
  }
  float acc[PX][12];
#pragma unroll
  for (int i = 0; i < PX; i++)
#pragma unroll
    for (int j = 0; j < 12; j++) acc[i][j] = b2[e*CC + ocg*12 + j];

  for (int ic = 0; ic < CC; ic++){
    const float* hc = hp + (size_t)ic*NP;
    float z[PX][9];
#pragma unroll
    for (int i = 0; i < PX; i++){
#pragma unroll
      for (int ky = 0; ky < 3; ky++){
        int yy = oyv[i] + ky - 1;
#pragma unroll
        for (int kx = 0; kx < 3; kx++){
          int xx = oxv[i] + kx - 1;
          z[i][ky*3+kx] = ((unsigned)yy < (unsigned)S && (unsigned)xx < (unsigned)S) ? hc[yy*S + xx] : 0.f;
        }
      }
    }
#pragma unroll
    for (int k = 0; k < 9; k++){
      const float* wr = &wl[(ic*9 + k)*12];
#pragma unroll
      for (int i = 0; i < PX; i++){
        float a = z[i][k];
#pragma unroll
        for (int j = 0; j < 12; j++) acc[i][j] += a*wr[j];
      }
    }
  }

#pragma unroll
  for (int i = 0; i < PX; i++){
    int lp = pxl[i];
#pragma unroll
    for (int j = 0; j < 12; j++) he[lp*13 + j] = acc[i][j];
  }
  __syncthreads();
  float* ob = out + (size_t)b*CC*NPIX;
  for (int it = 0; it < 16; it++){
    int op = threadIdx.x + 256*it;
    int y = op >> 6, x = op & 63;
    int y0,y1,x0,x1; float wy0,wy1,wx0,wx1;
    bl_coord(y, y0, y1, wy0, wy1);
    bl_coord(x, x0, x1, wx0, wx1);
#pragma unroll
    for (int j = 0; j < 12; j++){
      float v = wy0*(wx0*he[(y0*32+x0)*13+j] + wx1*he[(y0*32+x1)*13+j])
              + wy1*(wx0*he[(y1*32+x0)*13+j] + wx1*he[(y1*32+x1)*13+j]);
      int oc = ocg*12 + j;
      atomicAdd(&ob[(size_t)oc*NPIX + op], gt*v);
    }
  }
}

// ---------------- launch ---------------------------------------------------------
extern "C" void kernel_launch(void* const* d_in, const int* in_sizes, int n_in,
                              void* d_out, int out_size, void* d_ws, size_t ws_size,
                              hipStream_t stream) {
  const float* x      = (const float*)d_in[0];
  const float* text   = (const float*)d_in[1];
  const float* ln1w   = (const float*)d_in[3];
  const float* ln1b   = (const float*)d_in[4];
  const float* ln2w   = (const float*)d_in[5];
  const float* ln2b   = (const float*)d_in[6];
  const float* qkvw   = (const float*)d_in[7];
  const float* qkvdw  = (const float*)d_in[8];
  const float* projw  = (const float*)d_in[9];
  const float* routw  = (const float*)d_in[10];
  const float* gwx    = (const float*)d_in[11];
  const float* gwt    = (const float*)d_in[12];
  const float* ew1    = (const float*)d_in[13];
  const float* eb1    = (const float*)d_in[14];
  const float* ew2    = (const float*)d_in[15];
  const float* eb2    = (const float*)d_in[16];
  float* out = (float*)d_out;

  float* wsf = (float*)d_ws;
  float* y2      = wsf;                      // 786432 f
  float* pooled  = wsf + 786432;             // 192
  float* gates   = wsf + 786624;             // 64 (+pad to 786944)
  float* F       = wsf + 786944;
  float* qkv_raw = F;                        // 2359296
  float* qkv_dw  = F + 2359296;              // 2359296
  float* rl      = F + 4718592;              // 131072
  float* gmask   = F + 4849664;              // 131072
  float* attnout = F + 4980736;              // 786432 (front ends at F+5767168)
  float* part    = F + 5767168;              // 12288 (inside h region, used pre-experts)
  float* smg     = F + 5779456;              // 1152
  float* hbase   = F;                        // expert h slots (21430272 f)

  k_ln_qkv<<<dim3(8, SB, 6), 256, 0, stream>>>(x, ln1w, ln1b, qkvw, routw, qkv_raw, rl);
  k_dwconv<<<dim3(16, 144, SB), 256, 0, stream>>>(qkv_raw, qkvdw, qkv_dw);
  k_router_gates<<<dim3(64), 256, 0, stream>>>(rl, gmask);
  k_attn_part<<<dim3(8, NH, SB), 256, 0, stream>>>(qkv_dw, part);
  k_attn_soft<<<dim3(NH, SB), 64, 0, stream>>>(part, smg);
  k_attn_apply<<<dim3(16, NH, SB), 256, 0, stream>>>(qkv_dw, smg, gmask, attnout);
  k_proj_ln2<<<dim3(16, SB), 256, 0, stream>>>(attnout, x, projw, ln2w, ln2b, out, y2);
  k_pool<<<dim3(SB*CC), 256, 0, stream>>>(y2, pooled);
  k_moe_gate<<<dim3(1), 64, 0, stream>>>(pooled, text, gwx, gwt, gates);

  k_econv1u<<<dim3(64, SB, NE), 256, 0, stream>>>(y2, ew1, eb1, gates, hbase);
  k_econv2u<<<dim3(64, SB, NE), 256, 0, stream>>>(hbase, ew2, eb2, gates, out);
  k_econv2t2<<<dim3(4, SB, 5), 256, 0, stream>>>(hbase, ew2, eb2, gates, out);

  (void)in_sizes; (void)n_in; (void)out_size; (void)ws_size;
}

// Round 8
// 387.599 us; speedup vs baseline: 3.1291x; 1.5237x over previous
//
#include <hip/hip_runtime.h>
#include <math.h>

#define SB 4
#define CC 48
#define NH 8
#define HDIM 6
#define NPIX 4096
#define NE 16
#define TD 512

__device__ __forceinline__ float wave_sum(float t){
#pragma unroll
  for (int o = 32; o >= 1; o >>= 1) t += __shfl_xor(t, o, 64);
  return t;
}

__device__ __forceinline__ float gelu(float t){
  return 0.5f*t*(1.f + erff(t*0.70710678118654752f));
}

// acc[8] += z * w-row (2 float4 in scope: _w0,_w1)
#define ACC8(A, Z) { float _z=(Z); \
  A[0]+=_z*_w0.x; A[1]+=_z*_w0.y; A[2]+=_z*_w0.z; A[3]+=_z*_w0.w; \
  A[4]+=_z*_w1.x; A[5]+=_z*_w1.y; A[6]+=_z*_w1.z; A[7]+=_z*_w1.w; }

// ---------------- K1: LN1 + qkv/router 1x1, 6 oc-sections ------------------------
__global__ __launch_bounds__(256) void k_ln_qkv(
    const float* __restrict__ x, const float* __restrict__ ln1w, const float* __restrict__ ln1b,
    const float* __restrict__ qkvw, const float* __restrict__ routw,
    float* __restrict__ qkv_raw, float* __restrict__ rl)
{
  int sec = blockIdx.z;
  int NOC = (sec == 5) ? 32 : 24;
  __shared__ __align__(16) float wl[32*48];
  int tid = threadIdx.x;
  for (int i = tid; i < NOC*48; i += 256){
    int oc = i/48, c = i%48, og = sec*24 + oc;
    wl[i] = (og < 144) ? qkvw[og*48 + c] : routw[(og-144)*48 + c];
  }
  __syncthreads();
  int b = blockIdx.y;
  int p0 = blockIdx.x*512 + tid, p1 = p0 + 256;
  const float* xb = x + (size_t)b*CC*NPIX;
  float v0[48], v1[48];
  float mu0 = 0.f, mu1 = 0.f;
#pragma unroll
  for (int c = 0; c < CC; c++){
    v0[c] = xb[(size_t)c*NPIX + p0]; v1[c] = xb[(size_t)c*NPIX + p1];
    mu0 += v0[c]; mu1 += v1[c];
  }
  mu0 *= (1.f/CC); mu1 *= (1.f/CC);
  float va0 = 0.f, va1 = 0.f;
#pragma unroll
  for (int c = 0; c < CC; c++){
    float d0 = v0[c]-mu0, d1 = v1[c]-mu1; va0 += d0*d0; va1 += d1*d1;
  }
  float rs0 = rsqrtf(va0*(1.f/CC) + 1e-5f), rs1 = rsqrtf(va1*(1.f/CC) + 1e-5f);
#pragma unroll
  for (int c = 0; c < CC; c++){
    float w = ln1w[c], bb = ln1b[c];
    v0[c] = (v0[c]-mu0)*rs0*w + bb;
    v1[c] = (v1[c]-mu1)*rs1*w + bb;
  }
  float* qb = qkv_raw + (size_t)b*144*NPIX;
  float* rb = rl + (size_t)b*NH*NPIX;
  for (int oc = 0; oc < NOC; oc++){
    const float4* wv = (const float4*)&wl[oc*48];
    float s0 = 0.f, s1 = 0.f;
#pragma unroll
    for (int q = 0; q < 12; q++){
      float4 w = wv[q];
      s0 += w.x*v0[q*4] + w.y*v0[q*4+1] + w.z*v0[q*4+2] + w.w*v0[q*4+3];
      s1 += w.x*v1[q*4] + w.y*v1[q*4+1] + w.z*v1[q*4+2] + w.w*v1[q*4+3];
    }
    int og = sec*24 + oc;
    float* dst = (og < 144) ? (qb + (size_t)og*NPIX) : (rb + (size_t)(og-144)*NPIX);
    dst[p0] = s0; dst[p1] = s1;
  }
}

// ---------------- K2: depthwise 3x3, pad 1 --------------------------------------
__global__ __launch_bounds__(256) void k_dwconv(
    const float* __restrict__ in, const float* __restrict__ w, float* __restrict__ out)
{
  int ch = blockIdx.y, b = blockIdx.z;
  int p = blockIdx.x*256 + threadIdx.x;
  int y = p >> 6, xx = p & 63;
  const float* wc = w + ch*9;
  const float* ib = in + ((size_t)b*144 + ch)*NPIX;
  float acc = 0.f;
#pragma unroll
  for (int ky = 0; ky < 3; ky++){
    int yy = y + ky - 1;
    if ((unsigned)yy < 64u){
#pragma unroll
      for (int kx = 0; kx < 3; kx++){
        int xc = xx + kx - 1;
        if ((unsigned)xc < 64u) acc += wc[ky*3+kx]*ib[yy*64+xc];
      }
    }
  }
  out[((size_t)b*144 + ch)*NPIX + p] = acc;
}

// ---------------- K3: per-pixel head routing ------------------------------------
__global__ __launch_bounds__(256) void k_router_gates(
    const float* __restrict__ rl, float* __restrict__ g)
{
  int idx = blockIdx.x*256 + threadIdx.x;
  int b = idx >> 12, p = idx & (NPIX-1);
  const float* r = rl + (size_t)b*NH*NPIX + p;
  float l[NH];
  float mx = -1e30f;
#pragma unroll
  for (int h = 0; h < NH; h++){ l[h] = r[(size_t)h*NPIX]; mx = fmaxf(mx, l[h]); }
  float s = 0.f;
#pragma unroll
  for (int h = 0; h < NH; h++){ l[h] = __expf(l[h]-mx); s += l[h]; }
  int i1 = 0; float p1 = -1.f;
#pragma unroll
  for (int h = 0; h < NH; h++) if (l[h] > p1){ p1 = l[h]; i1 = h; }
  int i2 = -1; float p2 = -1.f;
#pragma unroll
  for (int h = 0; h < NH; h++) if (h != i1 && l[h] > p2){ p2 = l[h]; i2 = h; }
  float denom = p1 + p2;
  float* go = g + (size_t)b*NH*NPIX + p;
#pragma unroll
  for (int h = 0; h < NH; h++)
    go[(size_t)h*NPIX] = (h == i1 || h == i2) ? l[h]/denom : 0.f;
}

// ---------------- attention phase A: partial gram/norm sums ---------------------
__global__ __launch_bounds__(256) void k_attn_part(
    const float* __restrict__ qkv, float* __restrict__ part)
{
  int ch = blockIdx.x, h = blockIdx.y, b = blockIdx.z;
  const float* q = qkv + ((size_t)b*144 + h*HDIM)*NPIX;
  const float* k = qkv + ((size_t)b*144 + 48 + h*HDIM)*NPIX;
  int tid = threadIdx.x;
  float qq[HDIM] = {0}, kk[HDIM] = {0}, qk[HDIM*HDIM] = {0};
#pragma unroll
  for (int t = 0; t < 2; t++){
    int n = ch*512 + t*256 + tid;
    float qv[HDIM], kv[HDIM];
#pragma unroll
    for (int c = 0; c < HDIM; c++){ qv[c] = q[(size_t)c*NPIX + n]; kv[c] = k[(size_t)c*NPIX + n]; }
#pragma unroll
    for (int c = 0; c < HDIM; c++){
      qq[c] += qv[c]*qv[c]; kk[c] += kv[c]*kv[c];
#pragma unroll
      for (int d = 0; d < HDIM; d++) qk[c*HDIM+d] += qv[c]*kv[d];
    }
  }
#pragma unroll
  for (int c = 0; c < HDIM; c++){ qq[c] = wave_sum(qq[c]); kk[c] = wave_sum(kk[c]); }
#pragma unroll
  for (int i = 0; i < HDIM*HDIM; i++) qk[i] = wave_sum(qk[i]);
  __shared__ float red[4][48];
  int lane = tid & 63, wv = tid >> 6;
  if (lane == 0){
#pragma unroll
    for (int c = 0; c < HDIM; c++){ red[wv][c] = qq[c]; red[wv][6+c] = kk[c]; }
#pragma unroll
    for (int i = 0; i < HDIM*HDIM; i++) red[wv][12+i] = qk[i];
  }
  __syncthreads();
  if (tid < 48)
    part[((size_t)(b*NH+h)*8 + ch)*48 + tid] = red[0][tid]+red[1][tid]+red[2][tid]+red[3][tid];
}

// ---------------- attention phase B: softmax matrix -----------------------------
__global__ __launch_bounds__(64) void k_attn_soft(
    const float* __restrict__ part, float* __restrict__ smg)
{
  int h = blockIdx.x, b = blockIdx.y, tid = threadIdx.x;
  __shared__ float tot[48];
  if (tid < 48){
    float s = 0.f;
    for (int ch = 0; ch < 8; ch++) s += part[((size_t)(b*NH+h)*8 + ch)*48 + tid];
    tot[tid] = s;
  }
  __syncthreads();
  if (tid < HDIM){
    int c = tid;
    float qn = fmaxf(sqrtf(tot[c]), 1e-12f);
    float row[HDIM];
    float mx = -1e30f;
#pragma unroll
    for (int d = 0; d < HDIM; d++){
      float kn = fmaxf(sqrtf(tot[6+d]), 1e-12f);
      float a = tot[12 + c*HDIM + d] / (qn*kn) * 0.40824829046386307f;
      row[d] = a; mx = fmaxf(mx, a);
    }
    float s = 0.f;
#pragma unroll
    for (int d = 0; d < HDIM; d++){ row[d] = __expf(row[d]-mx); s += row[d]; }
#pragma unroll
    for (int d = 0; d < HDIM; d++) smg[(size_t)(b*NH+h)*36 + c*HDIM + d] = row[d]/s;
  }
}

// ---------------- attention phase C: apply sm·v × gate --------------------------
__global__ __launch_bounds__(256) void k_attn_apply(
    const float* __restrict__ qkv, const float* __restrict__ smg,
    const float* __restrict__ g, float* __restrict__ out)
{
  int h = blockIdx.y, b = blockIdx.z;
  __shared__ float sm[36];
  int tid = threadIdx.x;
  if (tid < 36) sm[tid] = smg[(size_t)(b*NH+h)*36 + tid];
  __syncthreads();
  int n = blockIdx.x*256 + tid;
  const float* v = qkv + ((size_t)b*144 + 96 + h*HDIM)*NPIX;
  float vv[HDIM];
#pragma unroll
  for (int d = 0; d < HDIM; d++) vv[d] = v[(size_t)d*NPIX + n];
  float gg = g[((size_t)b*NH + h)*NPIX + n];
  float* ob = out + ((size_t)b*CC + h*HDIM)*NPIX;
#pragma unroll
  for (int c = 0; c < HDIM; c++){
    float o = 0.f;
#pragma unroll
    for (int d = 0; d < HDIM; d++) o += sm[c*HDIM+d]*vv[d];
    ob[(size_t)c*NPIX + n] = o*gg;
  }
}

// ---------------- K5: proj 1x1 + residual + LN2 ----------------------------------
__global__ __launch_bounds__(256) void k_proj_ln2(
    const float* __restrict__ attn_out, const float* __restrict__ x,
    const float* __restrict__ projw, const float* __restrict__ ln2w, const float* __restrict__ ln2b,
    float* __restrict__ xout, float* __restrict__ y2)
{
  __shared__ __align__(16) float w[CC*CC];
  int tid = threadIdx.x;
  for (int i = tid; i < CC*CC; i += 256) w[i] = projw[i];
  __syncthreads();
  int b = blockIdx.y;
  int p = blockIdx.x*256 + tid;
  const float* ain = attn_out + (size_t)b*CC*NPIX + p;
  float a[CC];
#pragma unroll
  for (int c = 0; c < CC; c++) a[c] = ain[(size_t)c*NPIX];
  const float* xb = x + (size_t)b*CC*NPIX + p;
  float xv[CC];
  float mu = 0.f;
#pragma unroll
  for (int oc = 0; oc < CC; oc++){
    const float4* wr = (const float4*)&w[oc*CC];
    float acc = 0.f;
#pragma unroll
    for (int q = 0; q < 12; q++){
      float4 ww = wr[q];
      acc += ww.x*a[q*4] + ww.y*a[q*4+1] + ww.z*a[q*4+2] + ww.w*a[q*4+3];
    }
    float t = xb[(size_t)oc*NPIX] + acc;
    xv[oc] = t; mu += t;
  }
  mu *= (1.f/CC);
  float var = 0.f;
#pragma unroll
  for (int c = 0; c < CC; c++){ float d = xv[c]-mu; var += d*d; }
  var *= (1.f/CC);
  float rs = rsqrtf(var + 1e-5f);
  float* xo = xout + (size_t)b*CC*NPIX + p;
  float* yo = y2 + (size_t)b*CC*NPIX + p;
#pragma unroll
  for (int c = 0; c < CC; c++){
    xo[(size_t)c*NPIX] = xv[c];
    yo[(size_t)c*NPIX] = (xv[c]-mu)*rs*ln2w[c] + ln2b[c];
  }
}

// ---------------- K_pool --------------------------------------------------------
__global__ __launch_bounds__(256) void k_pool(const float* __restrict__ y2, float* __restrict__ pooled)
{
  int bc = blockIdx.x;
  const float* r = y2 + (size_t)bc*NPIX;
  float s = 0.f;
  for (int n = threadIdx.x; n < NPIX; n += 256) s += r[n];
  s = wave_sum(s);
  __shared__ float red[4];
  int lane = threadIdx.x & 63, wv = threadIdx.x >> 6;
  if (lane == 0) red[wv] = s;
  __syncthreads();
  if (threadIdx.x == 0) pooled[bc] = (red[0]+red[1]+red[2]+red[3]) * (1.f/NPIX);
}

// ---------------- K6: MoE gate (+ pair compaction: always exactly 8 pairs) ------
__global__ __launch_bounds__(64) void k_moe_gate(
    const float* __restrict__ pooled, const float* __restrict__ text,
    const float* __restrict__ gwx, const float* __restrict__ gwt,
    float* __restrict__ gates, int* __restrict__ pairs)
{
  int tid = threadIdx.x;
  int b = tid >> 4, e = tid & 15;
  float acc = 0.f;
  for (int c = 0; c < CC; c++) acc += pooled[b*CC + c]*gwx[c*NE + e];
  for (int d = 0; d < TD; d++) acc += text[b*TD + d]*gwt[d*NE + e];
  __shared__ float lg[SB][NE];
  lg[b][e] = acc;
  __syncthreads();
  if (tid < SB){
    int bb = tid;
    float mx = -1e30f;
    for (int i = 0; i < NE; i++) mx = fmaxf(mx, lg[bb][i]);
    float ex[NE]; float s = 0.f;
    for (int i = 0; i < NE; i++){ ex[i] = __expf(lg[bb][i]-mx); s += ex[i]; }
    int i1 = 0; float p1 = -1.f;
    for (int i = 0; i < NE; i++) if (ex[i] > p1){ p1 = ex[i]; i1 = i; }
    int i2 = -1; float p2 = -1.f;
    for (int i = 0; i < NE; i++) if (i != i1 && ex[i] > p2){ p2 = ex[i]; i2 = i; }
    float denom = p1 + p2;
    for (int i = 0; i < NE; i++)
      gates[bb*NE + i] = (i == i1 || i == i2) ? ex[i]/denom : 0.f;
    pairs[bb*2 + 0] = bb*NE + i1;
    pairs[bb*2 + 1] = bb*NE + i2;
  }
}

// ================= Expert path (batched h-slot packing) ==========================
__device__ __forceinline__ float* hslot(float* hb, int e, int b, int np){
  int t0c = (e+2)/3, t1c = (e+1)/3, t2c = e/3;
  size_t off = 4u*((size_t)t0c*196608u + (size_t)t1c*786432u + (size_t)t2c*49152u);
  return hb + off + (size_t)b*CC*np;
}

// ---- unified conv1 (+bias+gelu): grid (96, 8 pairs) -----------------------------
__global__ __launch_bounds__(256) void k_econv1u(
    const float* __restrict__ y2, const float* __restrict__ w1, const float* __restrict__ b1,
    const int* __restrict__ pairs, float* __restrict__ hbase)
{
  int pe = pairs[blockIdx.y];
  int b = pe >> 4, e = pe & 15, ty = e % 3;
  int nx = (ty == 0) ? 48 : ((ty == 1) ? 96 : 24);
  if ((int)blockIdx.x >= nx) return;
  int ocg = blockIdx.x % 6, band = blockIdx.x / 6, yb = band*8;
  int tid = threadIdx.x;

  __shared__ __align__(16) float smem[3456 + 2600];
  float* wl = smem; float* patch = smem + 3456;
  const float4* wv4 = (const float4*)wl;
  const float* wg = w1 + (size_t)e*CC*CC*9 + (size_t)(ocg*8)*CC*9;
  for (int i = tid; i < 3456; i += 256){
    int ic = i/72, r2 = i%72, k = r2/8, j = r2%8;
    wl[i] = wg[((size_t)j*CC + ic)*9 + k];
  }
  float bb[8];
#pragma unroll
  for (int j = 0; j < 8; j++) bb[j] = b1[e*CC + ocg*8 + j];
  const float* src = y2 + (size_t)b*CC*NPIX;

  if (ty == 0){
    float* hp = hslot(hbase, e, b, 4096);
    int r = tid >> 5, xp = (tid & 31)*2;
    float a0[8], a1[8];
#pragma unroll
    for (int j = 0; j < 8; j++){ a0[j] = bb[j]; a1[j] = bb[j]; }
    int ldso[10], srco[10];
#pragma unroll
    for (int q = 0; q < 10; q++){
      int i = tid + 256*q;
      int icl = i/640, rem = i%640, rr = rem>>6, cc = rem&63;
      int s = yb - 1 + rr;
      ldso[q] = icl*650 + rr*65 + cc;
      srco[q] = ((unsigned)s < 64u) ? (icl*NPIX + s*64 + cc) : -1;
    }
    float st[10];
#pragma unroll
    for (int q = 0; q < 10; q++) st[q] = (srco[q] >= 0) ? src[srco[q]] : 0.f;
    for (int icg = 0; icg < 12; icg++){
      __syncthreads();
#pragma unroll
      for (int q = 0; q < 10; q++) patch[ldso[q]] = st[q];
      if (icg < 11){
        const float* s2 = src + (size_t)(icg+1)*4*NPIX;
#pragma unroll
        for (int q = 0; q < 10; q++) st[q] = (srco[q] >= 0) ? s2[srco[q]] : 0.f;
      }
      __syncthreads();
#pragma unroll
      for (int icl = 0; icl < 4; icl++){
        const float* pp = patch + icl*650 + r*65;
        float zz[3][4];
#pragma unroll
        for (int dy = 0; dy < 3; dy++)
#pragma unroll
          for (int dx = 0; dx < 4; dx++){
            int xx = xp - 1 + dx;
            zz[dy][dx] = ((unsigned)xx < 64u) ? pp[dy*65 + xx] : 0.f;
          }
        int wb = ((icg*4+icl)*9)*2;
#pragma unroll
        for (int k = 0; k < 9; k++){
          float4 _w0 = wv4[wb + k*2], _w1 = wv4[wb + k*2 + 1];
          ACC8(a0, zz[k/3][k%3]);
          ACC8(a1, zz[k/3][k%3+1]);
        }
      }
    }
    int p0 = (yb + r)*64 + xp;
#pragma unroll
    for (int j = 0; j < 8; j++){
      int oc = ocg*8 + j;
      hp[(size_t)oc*4096 + p0]     = gelu(a0[j]);
      hp[(size_t)oc*4096 + p0 + 1] = gelu(a1[j]);
    }
  } else if (ty == 1){
    float* hp = hslot(hbase, e, b, 16384);
    int r = tid >> 5, xp = (tid & 31)*4;
    float ac[4][8];
#pragma unroll
    for (int i = 0; i < 4; i++)
#pragma unroll
      for (int j = 0; j < 8; j++) ac[i][j] = bb[j];
    int row0 = (yb >> 1) - 1;
    int ldso[6], srco[6];
#pragma unroll
    for (int q = 0; q < 6; q++){
      int i = tid + 256*q;
      int icl = i/384, rem = i%384, rr = rem>>6, cc = rem&63;
      int s = row0 + rr;
      ldso[q] = icl*390 + rr*65 + cc;
      srco[q] = ((unsigned)s < 64u) ? (icl*NPIX + s*64 + cc) : -1;
    }
    float st[6];
#pragma unroll
    for (int q = 0; q < 6; q++) st[q] = (srco[q] >= 0) ? src[srco[q]] : 0.f;
    for (int icg = 0; icg < 12; icg++){
      __syncthreads();
#pragma unroll
      for (int q = 0; q < 6; q++) patch[ldso[q]] = st[q];
      if (icg < 11){
        const float* s2 = src + (size_t)(icg+1)*4*NPIX;
#pragma unroll
        for (int q = 0; q < 6; q++) st[q] = (srco[q] >= 0) ? s2[srco[q]] : 0.f;
      }
      __syncthreads();
#pragma unroll
      for (int icl = 0; icl < 4; icl++){
        const float* pp = patch + icl*390;
        int lr[3];
#pragma unroll
        for (int dy = 0; dy < 3; dy++) lr[dy] = ((r + dy - 1) >> 1) + 1;
        float zz[3][6];
#pragma unroll
        for (int dy = 0; dy < 3; dy++)
#pragma unroll
          for (int dx = 0; dx < 6; dx++){
            int xx = xp - 1 + dx;
            zz[dy][dx] = ((unsigned)xx < 128u) ? pp[lr[dy]*65 + (xx>>1)] : 0.f;
          }
        int wb = ((icg*4+icl)*9)*2;
#pragma unroll
        for (int k = 0; k < 9; k++){
          float4 _w0 = wv4[wb + k*2], _w1 = wv4[wb + k*2 + 1];
          int ky = k/3, kx = k%3;
          ACC8(ac[0], zz[ky][kx]);
          ACC8(ac[1], zz[ky][kx+1]);
          ACC8(ac[2], zz[ky][kx+2]);
          ACC8(ac[3], zz[ky][kx+3]);
        }
      }
    }
#pragma unroll
    for (int i = 0; i < 4; i++){
      int p = (yb + r)*128 + xp + i;
#pragma unroll
      for (int j = 0; j < 8; j++)
        hp[(size_t)(ocg*8 + j)*16384 + p] = gelu(ac[i][j]);
    }
  } else {
    float* hp = hslot(hbase, e, b, 1024);
    int r = tid >> 5, xp = tid & 31;
    float ac[8];
#pragma unroll
    for (int j = 0; j < 8; j++) ac[j] = bb[j];
    int row0 = 2*yb - 2;
    int ldso[10], srco[10];
#pragma unroll
    for (int q = 0; q < 10; q++){
      int i = tid + 256*q;
      int icl = i/1280, rem = i%1280, rr = rem>>6, cc = rem&63;
      int s = row0 + rr;
      ldso[q] = icl*1300 + rr*65 + cc;
      srco[q] = ((unsigned)s < 64u) ? (icl*NPIX + s*64 + cc) : -1;
    }
    float st[10];
#pragma unroll
    for (int q = 0; q < 10; q++) st[q] = (srco[q] >= 0) ? src[srco[q]] : 0.f;
    for (int icg = 0; icg < 24; icg++){
      __syncthreads();
#pragma unroll
      for (int q = 0; q < 10; q++) patch[ldso[q]] = st[q];
      if (icg < 23){
        const float* s2 = src + (size_t)(icg+1)*2*NPIX;
#pragma unroll
        for (int q = 0; q < 10; q++) st[q] = (srco[q] >= 0) ? s2[srco[q]] : 0.f;
      }
      __syncthreads();
#pragma unroll
      for (int icl = 0; icl < 2; icl++){
        const float* pp = patch + icl*1300;
        float zz[3][3];
#pragma unroll
        for (int dy = 0; dy < 3; dy++){
          int sy = yb + r + dy - 1;
          int pr2 = 2*(r + dy - 1) + 2;
#pragma unroll
          for (int dx = 0; dx < 3; dx++){
            int sx = xp + dx - 1;
            float m = 0.f;
            if ((unsigned)sy < 32u && (unsigned)sx < 32u){
              int c2 = 2*sx;
              m = fmaxf(fmaxf(pp[pr2*65+c2], pp[pr2*65+c2+1]),
                        fmaxf(pp[(pr2+1)*65+c2], pp[(pr2+1)*65+c2+1]));
            }
            zz[dy][dx] = m;
          }
        }
        int wb = ((icg*2+icl)*9)*2;
#pragma unroll
        for (int k = 0; k < 9; k++){
          float4 _w0 = wv4[wb + k*2], _w1 = wv4[wb + k*2 + 1];
          ACC8(ac, zz[k/3][k%3]);
        }
      }
    }
    int p = (yb + r)*32 + xp;
#pragma unroll
    for (int j = 0; j < 8; j++)
      hp[(size_t)(ocg*8 + j)*1024 + p] = gelu(ac[j]);
  }
}

// ---- unified conv2 (+bias, fused tails) all types: grid (96, 8 pairs) -----------
__device__ __forceinline__ void bl_coord(int o, int& i0, int& i1, float& w0, float& w1){
  float f = 0.5f*o - 0.25f;
  float fl = floorf(f);
  int i = (int)fl;
  float fr = f - fl;
  i0 = i < 0 ? 0 : i;
  int j = i + 1;
  i1 = j > 31 ? 31 : j;
  w0 = 1.f - fr; w1 = fr;
}

__global__ __launch_bounds__(256) void k_econv2u(
    const float* __restrict__ hbase, const float* __restrict__ w2, const float* __restrict__ b2,
    const float* __restrict__ gates, const int* __restrict__ pairs, float* __restrict__ out)
{
  int pe = pairs[blockIdx.y];
  int b = pe >> 4, e = pe & 15, ty = e % 3;
  int nx = (ty == 0) ? 48 : ((ty == 1) ? 96 : 6);
  if ((int)blockIdx.x >= nx) return;
  float gt = gates[b*NE + e];
  int ocg = (ty == 2) ? blockIdx.x : (blockIdx.x % 6);
  int band = (ty == 2) ? 0 : (blockIdx.x / 6);
  int yb = band*8;
  int tid = threadIdx.x;

  __shared__ __align__(16) float smem[3456 + 9216];
  float* wl = smem; float* patch = smem + 3456;
  const float4* wv4 = (const float4*)wl;
  const float* wg = w2 + (size_t)e*CC*CC*9 + (size_t)(ocg*8)*CC*9;
  for (int i = tid; i < 3456; i += 256){
    int ic = i/72, r2 = i%72, k = r2/8, j = r2%8;
    wl[i] = wg[((size_t)j*CC + ic)*9 + k];
  }
  float bb[8];
#pragma unroll
  for (int j = 0; j < 8; j++) bb[j] = b2[e*CC + ocg*8 + j];
  float* ob = out + (size_t)b*CC*NPIX;

  if (ty == 0){
    const float* src = hslot((float*)hbase, e, b, 4096);
    int r = tid >> 5, xp = (tid & 31)*2;
    float a0[8], a1[8];
#pragma unroll
    for (int j = 0; j < 8; j++){ a0[j] = bb[j]; a1[j] = bb[j]; }
    int ldso[10], srco[10];
#pragma unroll
    for (int q = 0; q < 10; q++){
      int i = tid + 256*q;
      int icl = i/640, rem = i%640, rr = rem>>6, cc = rem&63;
      int s = yb - 1 + rr;
      ldso[q] = icl*650 + rr*65 + cc;
      srco[q] = ((unsigned)s < 64u) ? (icl*4096 + s*64 + cc) : -1;
    }
    float st[10];
#pragma unroll
    for (int q = 0; q < 10; q++) st[q] = (srco[q] >= 0) ? src[srco[q]] : 0.f;
    for (int icg = 0; icg < 12; icg++){
      __syncthreads();
#pragma unroll
      for (int q = 0; q < 10; q++) patch[ldso[q]] = st[q];
      if (icg < 11){
        const float* s2 = src + (size_t)(icg+1)*4*4096;
#pragma unroll
        for (int q = 0; q < 10; q++) st[q] = (srco[q] >= 0) ? s2[srco[q]] : 0.f;
      }
      __syncthreads();
#pragma unroll
      for (int icl = 0; icl < 4; icl++){
        const float* pp = patch + icl*650 + r*65;
        float zz[3][4];
#pragma unroll
        for (int dy = 0; dy < 3; dy++)
#pragma unroll
          for (int dx = 0; dx < 4; dx++){
            int xx = xp - 1 + dx;
            zz[dy][dx] = ((unsigned)xx < 64u) ? pp[dy*65 + xx] : 0.f;
          }
        int wb = ((icg*4+icl)*9)*2;
#pragma unroll
        for (int k = 0; k < 9; k++){
          float4 _w0 = wv4[wb + k*2], _w1 = wv4[wb + k*2 + 1];
          ACC8(a0, zz[k/3][k%3]);
          ACC8(a1, zz[k/3][k%3+1]);
        }
      }
    }
    int p0 = (yb + r)*64 + xp;
#pragma unroll
    for (int j = 0; j < 8; j++){
      int oc = ocg*8 + j;
      atomicAdd(&ob[(size_t)oc*4096 + p0],     gt*a0[j]);
      atomicAdd(&ob[(size_t)oc*4096 + p0 + 1], gt*a1[j]);
    }
  } else if (ty == 1){
    const float* src = hslot((float*)hbase, e, b, 16384);
    int r = tid >> 5, xp = (tid & 31)*4;
    float ac[4][8];
#pragma unroll
    for (int i = 0; i < 4; i++)
#pragma unroll
      for (int j = 0; j < 8; j++) ac[i][j] = bb[j];
    int ldso[10], srco[10];
#pragma unroll
    for (int q = 0; q < 10; q++){
      int i = tid + 256*q;
      int icl = i/1280, rem = i%1280, rr = rem>>7, cc = rem&127;
      int s = yb - 1 + rr;
      ldso[q] = icl*1290 + rr*129 + cc;
      srco[q] = ((unsigned)s < 128u) ? (icl*16384 + s*128 + cc) : -1;
    }
    float st[10];
#pragma unroll
    for (int q = 0; q < 10; q++) st[q] = (srco[q] >= 0) ? src[srco[q]] : 0.f;
    for (int icg = 0; icg < 24; icg++){
      __syncthreads();
#pragma unroll
      for (int q = 0; q < 10; q++) patch[ldso[q]] = st[q];
      if (icg < 23){
        const float* s2 = src + (size_t)(icg+1)*2*16384;
#pragma unroll
        for (int q = 0; q < 10; q++) st[q] = (srco[q] >= 0) ? s2[srco[q]] : 0.f;
      }
      __syncthreads();
#pragma unroll
      for (int icl = 0; icl < 2; icl++){
        const float* pp = patch + icl*1290 + r*129;
        float zz[3][6];
#pragma unroll
        for (int dy = 0; dy < 3; dy++)
#pragma unroll
          for (int dx = 0; dx < 6; dx++){
            int xx = xp - 1 + dx;
            zz[dy][dx] = ((unsigned)xx < 128u) ? pp[dy*129 + xx] : 0.f;
          }
        int wb = ((icg*2+icl)*9)*2;
#pragma unroll
        for (int k = 0; k < 9; k++){
          float4 _w0 = wv4[wb + k*2], _w1 = wv4[wb + k*2 + 1];
          int ky = k/3, kx = k%3;
          ACC8(ac[0], zz[ky][kx]);
          ACC8(ac[1], zz[ky][kx+1]);
          ACC8(ac[2], zz[ky][kx+2]);
          ACC8(ac[3], zz[ky][kx+3]);
        }
      }
    }
    // fused 2x2 maxpool: horizontal in-reg, vertical via shfl_xor(32)
    int pr = (yb + r) >> 1;
    int c0 = xp >> 1;
#pragma unroll
    for (int j = 0; j < 8; j++){
      float m0 = fmaxf(ac[0][j], ac[1][j]);
      float m1 = fmaxf(ac[2][j], ac[3][j]);
      float o0 = fmaxf(m0, __shfl_xor(m0, 32, 64));
      float o1 = fmaxf(m1, __shfl_xor(m1, 32, 64));
      if ((r & 1) == 0){
        int oc = ocg*8 + j;
        atomicAdd(&ob[(size_t)oc*4096 + pr*64 + c0],     gt*o0);
        atomicAdd(&ob[(size_t)oc*4096 + pr*64 + c0 + 1], gt*o1);
      }
    }
  } else {
    // whole 32x32 image per block; bilinear-up fused
    const float* src = hslot((float*)hbase, e, b, 1024);
    float ac[4][8];
#pragma unroll
    for (int i = 0; i < 4; i++)
#pragma unroll
      for (int j = 0; j < 8; j++) ac[i][j] = bb[j];
    float st[8];
#pragma unroll
    for (int q = 0; q < 8; q++){
      int i = tid + 256*q;
      st[q] = src[i];      // icl*1024 + p == i
    }
    for (int icg = 0; icg < 24; icg++){
      __syncthreads();
#pragma unroll
      for (int q = 0; q < 8; q++) patch[tid + 256*q] = st[q];
      if (icg < 23){
        const float* s2 = src + (size_t)(icg+1)*2*1024;
#pragma unroll
        for (int q = 0; q < 8; q++) st[q] = s2[tid + 256*q];
      }
      __syncthreads();
#pragma unroll
      for (int icl = 0; icl < 2; icl++){
        const float* pp = patch + icl*1024;
        int wb0 = ((icg*2+icl)*9)*2;
#pragma unroll
        for (int ii = 0; ii < 4; ii++){
          int l = tid + 256*ii;
          int oy = l >> 5, ox = l & 31;
#pragma unroll
          for (int k = 0; k < 9; k++){
            int ky = k/3, kx = k%3;
            int yy = oy + ky - 1, xx = ox + kx - 1;
            float z = ((unsigned)yy < 32u && (unsigned)xx < 32u) ? pp[yy*32 + xx] : 0.f;
            float4 _w0 = wv4[wb0 + k*2], _w1 = wv4[wb0 + k*2 + 1];
            ACC8(ac[ii], z);
          }
        }
      }
    }
    __syncthreads();   // patch dead; reuse as he[1024][9]
    float* he = patch;
#pragma unroll
    for (int ii = 0; ii < 4; ii++){
      int l = tid + 256*ii;
#pragma unroll
      for (int j = 0; j < 8; j++) he[l*9 + j] = ac[ii][j];
    }
    __syncthreads();
    for (int it = 0; it < 16; it++){
      int op = tid + 256*it;
      int y = op >> 6, x = op & 63;
      int y0,y1,x0,x1; float wy0,wy1,wx0,wx1;
      bl_coord(y, y0, y1, wy0, wy1);
      bl_coord(x, x0, x1, wx0, wx1);
#pragma unroll
      for (int j = 0; j < 8; j++){
        float v = wy0*(wx0*he[(y0*32+x0)*9+j] + wx1*he[(y0*32+x1)*9+j])
                + wy1*(wx0*he[(y1*32+x0)*9+j] + wx1*he[(y1*32+x1)*9+j]);
        int oc = ocg*8 + j;
        atomicAdd(&ob[(size_t)oc*NPIX + op], gt*v);
      }
    }
  }
}

// ---------------- launch ---------------------------------------------------------
extern "C" void kernel_launch(void* const* d_in, const int* in_sizes, int n_in,
                              void* d_out, int out_size, void* d_ws, size_t ws_size,
                              hipStream_t stream) {
  const float* x      = (const float*)d_in[0];
  const float* text   = (const float*)d_in[1];
  const float* ln1w   = (const float*)d_in[3];
  const float* ln1b   = (const float*)d_in[4];
  const float* ln2w   = (const float*)d_in[5];
  const float* ln2b   = (const float*)d_in[6];
  const float* qkvw   = (const float*)d_in[7];
  const float* qkvdw  = (const float*)d_in[8];
  const float* projw  = (const float*)d_in[9];
  const float* routw  = (const float*)d_in[10];
  const float* gwx    = (const float*)d_in[11];
  const float* gwt    = (const float*)d_in[12];
  const float* ew1    = (const float*)d_in[13];
  const float* eb1    = (const float*)d_in[14];
  const float* ew2    = (const float*)d_in[15];
  const float* eb2    = (const float*)d_in[16];
  float* out = (float*)d_out;

  float* wsf = (float*)d_ws;
  float* y2      = wsf;                      // 786432 f
  float* pooled  = wsf + 786432;             // 192
  float* gates   = wsf + 786624;             // 64
  int*   pairs   = (int*)(wsf + 786688);     // 8 ints
  float* F       = wsf + 786944;
  float* qkv_raw = F;                        // 2359296
  float* qkv_dw  = F + 2359296;              // 2359296
  float* rl      = F + 4718592;              // 131072
  float* gmask   = F + 4849664;              // 131072
  float* attnout = F + 4980736;              // 786432 (front ends at F+5767168)
  float* part    = F + 5767168;              // 12288
  float* smg     = F + 5779456;              // 1152
  float* hbase   = F;                        // expert h slots (21430272 f)

  k_ln_qkv<<<dim3(8, SB, 6), 256, 0, stream>>>(x, ln1w, ln1b, qkvw, routw, qkv_raw, rl);
  k_dwconv<<<dim3(16, 144, SB), 256, 0, stream>>>(qkv_raw, qkvdw, qkv_dw);
  k_router_gates<<<dim3(64), 256, 0, stream>>>(rl, gmask);
  k_attn_part<<<dim3(8, NH, SB), 256, 0, stream>>>(qkv_dw, part);
  k_attn_soft<<<dim3(NH, SB), 64, 0, stream>>>(part, smg);
  k_attn_apply<<<dim3(16, NH, SB), 256, 0, stream>>>(qkv_dw, smg, gmask, attnout);
  k_proj_ln2<<<dim3(16, SB), 256, 0, stream>>>(attnout, x, projw, ln2w, ln2b, out, y2);
  k_pool<<<dim3(SB*CC), 256, 0, stream>>>(y2, pooled);
  k_moe_gate<<<dim3(1), 64, 0, stream>>>(pooled, text, gwx, gwt, gates, pairs);

  k_econv1u<<<dim3(96, 8), 256, 0, stream>>>(y2, ew1, eb1, pairs, hbase);
  k_econv2u<<<dim3(96, 8), 256, 0, stream>>>(hbase, ew2, eb2, gates, pairs, out);

  (void)in_sizes; (void)n_in; (void)out_size; (void)ws_size;
}